// Round 6
// baseline (434.095 us; speedup 1.0000x reference)
//
#include <hip/hip_runtime.h>
#include <hip/hip_bf16.h>

// ---------------------------------------------------------------------------
// GIN encoder. Residual stream in bf16 only (ping-pong A/B).
// Fused per-layer kernel (k_layer): gather + MLP + residual.
// Round 6: revert gather to the round-4 winner (4 static streams x 2
// episodes, adj-index prefetch only; depth-2 row pipelining of round 5
// REGRESSED: VGPR 40->80, occupancy 38->23%, dur 41->47 us). Buy TLP
// instead of ILP: drop sSelf (epilogue re-reads hb_in coalesced),
// LDS 34.3->25.6 KB -> 6 blocks/CU, __launch_bounds__(256,6).
// Launch count cut 15->12: (hist|pack) and (fill|encoder) merged.
// ---------------------------------------------------------------------------

typedef short bf16x8 __attribute__((ext_vector_type(8)));
typedef unsigned short u16x8 __attribute__((ext_vector_type(8)));
typedef float f32x4 __attribute__((ext_vector_type(4)));

__device__ __forceinline__ float bs2f(unsigned short u) {
    return __uint_as_float(((unsigned)u) << 16);
}
__device__ __forceinline__ unsigned short f2bs(float f) {
    __hip_bfloat16 h = __float2bfloat16(f);
    return *reinterpret_cast<unsigned short*>(&h);
}

// masked packed unpack-accumulate: msk=~0u accumulates, 0u adds +0.0f
__device__ __forceinline__ void accm(float* acc, u16x8 v, unsigned msk) {
    union { u16x8 u; unsigned int w[4]; } cv;
    cv.u = v;
#pragma unroll
    for (int k = 0; k < 4; k++) {
        unsigned int d = cv.w[k] & msk;
        acc[2 * k]     += __uint_as_float(d << 16);
        acc[2 * k + 1] += __uint_as_float(d & 0xffff0000u);
    }
}

// ---------------- CSR scan kernels ----------------
__global__ __launch_bounds__(256) void k_scanA(const int* __restrict__ deg,
                                               int* __restrict__ partials, int n)
{
    int i = blockIdx.x * 256 + threadIdx.x;
    int v = (i < n) ? deg[i] : 0;
#pragma unroll
    for (int off = 32; off >= 1; off >>= 1) v += __shfl_down(v, off, 64);
    __shared__ int ws[4];
    int wave = threadIdx.x >> 6;
    if ((threadIdx.x & 63) == 0) ws[wave] = v;
    __syncthreads();
    if (threadIdx.x == 0)
        partials[blockIdx.x] = ws[0] + ws[1] + ws[2] + ws[3];
}

__global__ __launch_bounds__(256) void k_scanC(const int* __restrict__ deg,
                                               const int* __restrict__ partials,
                                               int* __restrict__ rowptr,
                                               int* __restrict__ cursor,
                                               int n, int nb)
{
    __shared__ int sp[256];
    __shared__ int s[256];
    int t = threadIdx.x;
    int pv = (t < nb) ? partials[t] : 0;
    sp[t] = pv;
    __syncthreads();
    for (int off = 1; off < 256; off <<= 1) {
        int u = (t >= off) ? sp[t - off] : 0;
        __syncthreads();
        sp[t] += u;
        __syncthreads();
    }
    int base = (blockIdx.x == 0) ? 0 : sp[blockIdx.x - 1];
    int i = blockIdx.x * 256 + t;
    int v = (i < n) ? deg[i] : 0;
    s[t] = v;
    __syncthreads();
    for (int off = 1; off < 256; off <<= 1) {
        int u = (t >= off) ? s[t - off] : 0;
        __syncthreads();
        s[t] += u;
        __syncthreads();
    }
    int inc = s[t];
    if (i < n) {
        int ex = base + inc - v;
        rowptr[i] = ex;
        cursor[i] = ex;
        if (i == n - 1) rowptr[n] = base + inc;
    }
}

// ---------------- weight packing helper ----------------
__device__ __forceinline__ void pack_one(const float* __restrict__ W,
                                         short* __restrict__ P,
                                         int id, int Kt, int Nt)
{
    int lane = id & 63;
    int t = id >> 6;
    int kt = t % Kt; t /= Kt;
    int nt = t % Nt; int l = t / Nt;
    int K = Kt * 32, N = Nt * 16;
    const float* Wl = W + (size_t)l * K * N;
    int n = nt * 16 + (lane & 15);
    int kbase = kt * 32 + (lane >> 4) * 8;
    bf16x8 v;
#pragma unroll
    for (int j = 0; j < 8; j++)
        v[j] = (short)f2bs(Wl[(size_t)(kbase + j) * N + n]);
    *(bf16x8*)(P + (size_t)id * 8) = v;
}

#define PK1 16384   // 4 layers * Nt16 * Kt4 * 64
#define PK2 16384   // 4 layers * Nt8  * Kt8 * 64
#define PK0 2048    // 1 layer  * Nt8  * Kt4 * 64

// ---------------- merged: edge histogram | weight packing ----------------
__global__ __launch_bounds__(256) void k_prep_a(
    const int* __restrict__ dst, int* __restrict__ deg, int nE,
    const float* __restrict__ mlpW1, const float* __restrict__ mlpW2,
    const float* __restrict__ W0,
    short* __restrict__ pW1, short* __restrict__ pW2, short* __restrict__ pW0,
    int histBlocks)
{
    if ((int)blockIdx.x < histBlocks) {
        int i = blockIdx.x * 256 + threadIdx.x;
        if (i < nE) atomicAdd(&deg[dst[i]], 1);
    } else {
        int id = (blockIdx.x - histBlocks) * 256 + threadIdx.x;
        if (id < PK1) {
            pack_one(mlpW1, pW1, id, 4, 16);
        } else if (id < PK1 + PK2) {
            pack_one(mlpW2, pW2, id - PK1, 8, 8);
        } else if (id < PK1 + PK2 + PK0) {
            pack_one(W0, pW0, id - PK1 - PK2, 4, 8);
        }
    }
}

// ---------------- merged: CSR fill | encoder ----------------
// encoder: hb = bf16(x@W0 + b0) via MFMA
__global__ __launch_bounds__(256) void k_prep_b(
    const int* __restrict__ src, const int* __restrict__ dst,
    int* __restrict__ cursor, int* __restrict__ adj, int nE,
    const float* __restrict__ x, const short* __restrict__ pW0,
    const float* __restrict__ b0, unsigned short* __restrict__ hb, int n,
    int fillBlocks)
{
    __shared__ unsigned short sX[32][136];
    if ((int)blockIdx.x < fillBlocks) {
        int i = blockIdx.x * 256 + threadIdx.x;
        if (i < nE) {
            int pos = atomicAdd(&cursor[dst[i]], 1);
            adj[pos] = src[i];
        }
        return;
    }
    const int t = threadIdx.x;
    const int w = t >> 6;
    const int L = t & 63;
    const int node0 = (blockIdx.x - fillBlocks) * 32;

    const float4* x4 = (const float4*)x;
    for (int i = t; i < 32 * 32; i += 256) {
        int m = i >> 5, cgi = i & 31;
        int node = node0 + m;
        float4 v = make_float4(0.f, 0.f, 0.f, 0.f);
        if (node < n) v = x4[(size_t)node * 32 + cgi];
        ushort4 p;
        p.x = f2bs(v.x); p.y = f2bs(v.y); p.z = f2bs(v.z); p.w = f2bs(v.w);
        *(ushort4*)&sX[m][cgi * 4] = p;
    }
    __syncthreads();

    const int quad = L >> 4;
    const int l16 = L & 15;
    const bf16x8* base = (const bf16x8*)pW0;

#pragma unroll
    for (int jj = 0; jj < 2; jj++) {
        int nt = w * 2 + jj;
        bf16x8 b[4];
#pragma unroll
        for (int kt = 0; kt < 4; kt++)
            b[kt] = base[(size_t)(nt * 4 + kt) * 64 + L];
        int c = nt * 16 + l16;
        float bc = b0[c];
#pragma unroll
        for (int hh = 0; hh < 2; hh++) {
            int mh = hh * 16;
            f32x4 acc = {0.f, 0.f, 0.f, 0.f};
#pragma unroll
            for (int kt = 0; kt < 4; kt++) {
                bf16x8 a = *(const bf16x8*)&sX[mh + l16][kt * 32 + quad * 8];
                acc = __builtin_amdgcn_mfma_f32_16x16x32_bf16(a, b[kt], acc, 0, 0, 0);
            }
#pragma unroll
            for (int r = 0; r < 4; r++) {
                int node = node0 + mh + quad * 4 + r;
                if (node < n)
                    hb[(size_t)node * 128 + c] = f2bs(acc[r] + bc);
            }
        }
    }
}

// ---------------- fused layer: gather + MLP + residual --------------------
// hb_out = hb_in + relu(BN2(W2 relu(BN1(W1 (hb_in + sum_neighbors)))))
// Gather: 4 static streams/wave (rows ep*4+{0..3}) x 2 episodes, clamped+
// masked 4-edge chunks (unroll-2 per stream), adj prefetched one chunk
// ahead. Lane layout: g = L>>4 picks 1 of 4 edges in the chunk, l16 = L&15
// is the 16B channel segment; 16 lanes cover one 256B node row.
// LDS 25.6 KB -> 6 blocks/CU; launch_bounds(256,6) caps VGPR at 85
// (round-4 codegen used 80 at a relaxed bound, so this fits).
__global__ __launch_bounds__(256, 6) void k_layer(
    const unsigned short* __restrict__ hb_in,
    unsigned short* __restrict__ hb_out,
    const int* __restrict__ rowptr, const int* __restrict__ adj,
    const short* __restrict__ pW1, const float* __restrict__ b1,
    const float* __restrict__ g1, const float* __restrict__ be1,
    const float* __restrict__ mu1, const float* __restrict__ va1,
    const short* __restrict__ pW2, const float* __restrict__ b2,
    const float* __restrict__ g2, const float* __restrict__ be2,
    const float* __restrict__ mu2, const float* __restrict__ va2,
    int n)
{
    __shared__ unsigned short sIn[32][136];    // gathered agg; reused for m out
    __shared__ unsigned short sMid[32][264];   // bf16 MLP hidden, pad 8
    const int t = threadIdx.x;
    const int w = t >> 6;
    const int L = t & 63;
    const int node0 = blockIdx.x * 32;
    const int g = L >> 4;
    const int l16 = L & 15;
    const int wrow = w * 8;

    // ---- gather phase: wave w fills sIn rows wrow..wrow+7 ----
    {
        const u16x8* hb8 = (const u16x8*)hb_in;
        const int base = node0 + wrow;

        // rowptr[base .. base+8], index-clamped so OOB rows degenerate
        // to empty ranges (rowptr[n] repeated).
        int rp[9];
#pragma unroll
        for (int j = 0; j < 9; j++) {
            int idx = base + j;
            rp[j] = rowptr[idx > n ? n : idx];
        }

#define CHUNK_INIT(S, EE, QQ)                                               \
        int e##S = (EE), q##S = (QQ);                                       \
        bool ok##S = e##S < q##S;                                           \
        int x##S##0 = e##S + g, x##S##1 = e##S + 4 + g;                     \
        int i##S##0 = adj[ok##S ? (x##S##0 < q##S ? x##S##0 : q##S - 1) : 0]; \
        int i##S##1 = adj[ok##S ? (x##S##1 < q##S ? x##S##1 : q##S - 1) : 0]; \
        float acc##S[8] = {0.f,0.f,0.f,0.f,0.f,0.f,0.f,0.f};

#define CHUNK_LOAD(S)                                                       \
        u16x8 r##S##0 = hb8[(unsigned)i##S##0 * 16u + l16];                 \
        u16x8 r##S##1 = hb8[(unsigned)i##S##1 * 16u + l16];

#define CHUNK_MASK(S)                                                       \
        unsigned m##S##0 = (ok##S && e##S + g < q##S)     ? ~0u : 0u;       \
        unsigned m##S##1 = (ok##S && e##S + 4 + g < q##S) ? ~0u : 0u;

#define CHUNK_PREF(S)                                                       \
        int ne##S = ok##S ? e##S + 8 : e##S;                                \
        bool nok##S = ne##S < q##S;                                         \
        int nx##S##0 = ne##S + g, nx##S##1 = ne##S + 4 + g;                 \
        int ni##S##0 = adj[nok##S ? (nx##S##0 < q##S ? nx##S##0 : q##S - 1) : 0]; \
        int ni##S##1 = adj[nok##S ? (nx##S##1 < q##S ? nx##S##1 : q##S - 1) : 0];

#define CHUNK_ACC(S)                                                        \
        accm(acc##S, r##S##0, m##S##0);                                     \
        accm(acc##S, r##S##1, m##S##1);

#define CHUNK_ROT(S)                                                        \
        e##S = ne##S; ok##S = nok##S; i##S##0 = ni##S##0; i##S##1 = ni##S##1;

#define SELF_LOAD(S, NODE)                                                  \
        u16x8 self##S;                                                      \
        {                                                                   \
            _Pragma("unroll")                                               \
            for (int j = 0; j < 8; j++) self##S[j] = 0;                     \
            if ((NODE) < n) self##S = hb8[(unsigned)(NODE) * 16u + l16];    \
        }

#define STREAM_FIN(S, ROWIDX)                                               \
        {                                                                   \
            u16x8 o;                                                        \
            _Pragma("unroll")                                               \
            for (int j = 0; j < 8; j++) {                                   \
                float vv = acc##S[j];                                       \
                vv += __shfl_xor(vv, 16, 64);                               \
                vv += __shfl_xor(vv, 32, 64);                               \
                o[j] = f2bs(vv + bs2f(self##S[j]));                         \
            }                                                               \
            if (g == 0) *(u16x8*)&sIn[(ROWIDX)][l16 * 8] = o;               \
        }

#pragma unroll
        for (int ep = 0; ep < 2; ep++) {
            const int r0 = ep * 4;
            CHUNK_INIT(A, rp[r0 + 0], rp[r0 + 1])
            CHUNK_INIT(B, rp[r0 + 1], rp[r0 + 2])
            CHUNK_INIT(C, rp[r0 + 2], rp[r0 + 3])
            CHUNK_INIT(D, rp[r0 + 3], rp[r0 + 4])

            while (okA | okB | okC | okD) {
                CHUNK_LOAD(A) CHUNK_LOAD(B) CHUNK_LOAD(C) CHUNK_LOAD(D)
                CHUNK_MASK(A) CHUNK_MASK(B) CHUNK_MASK(C) CHUNK_MASK(D)
                CHUNK_PREF(A) CHUNK_PREF(B) CHUNK_PREF(C) CHUNK_PREF(D)
                CHUNK_ACC(A) CHUNK_ACC(B) CHUNK_ACC(C) CHUNK_ACC(D)
                CHUNK_ROT(A) CHUNK_ROT(B) CHUNK_ROT(C) CHUNK_ROT(D)
            }

            SELF_LOAD(A, base + r0 + 0)
            SELF_LOAD(B, base + r0 + 1)
            SELF_LOAD(C, base + r0 + 2)
            SELF_LOAD(D, base + r0 + 3)
            STREAM_FIN(A, wrow + r0 + 0)
            STREAM_FIN(B, wrow + r0 + 1)
            STREAM_FIN(C, wrow + r0 + 2)
            STREAM_FIN(D, wrow + r0 + 3)
        }
#undef CHUNK_INIT
#undef CHUNK_LOAD
#undef CHUNK_MASK
#undef CHUNK_PREF
#undef CHUNK_ACC
#undef CHUNK_ROT
#undef SELF_LOAD
#undef STREAM_FIN
    }
    __syncthreads();

    const int quad = L >> 4;

    // ---- phase 1: sMid = relu(BN1(sIn @ W1 + b1)), 32x256, K=128 ----
    {
        const bf16x8* base1 = (const bf16x8*)pW1;
#pragma unroll
        for (int j = 0; j < 4; j++) {
            int nt = w * 4 + j;
            bf16x8 b[4];
#pragma unroll
            for (int kt = 0; kt < 4; kt++)
                b[kt] = base1[(size_t)(nt * 4 + kt) * 64 + L];
            int c = nt * 16 + l16;
            float sc = g1[c] * rsqrtf(va1[c] + 1e-5f);
            float sh = (b1[c] - mu1[c]) * sc + be1[c];
#pragma unroll
            for (int hh = 0; hh < 2; hh++) {
                int mh = hh * 16;
                f32x4 acc = {0.f, 0.f, 0.f, 0.f};
#pragma unroll
                for (int kt = 0; kt < 4; kt++) {
                    bf16x8 a = *(const bf16x8*)&sIn[mh + l16][kt * 32 + quad * 8];
                    acc = __builtin_amdgcn_mfma_f32_16x16x32_bf16(a, b[kt], acc, 0, 0, 0);
                }
#pragma unroll
                for (int r = 0; r < 4; r++) {
                    float v = fmaxf(acc[r] * sc + sh, 0.f);
                    sMid[mh + quad * 4 + r][c] = f2bs(v);
                }
            }
        }
    }
    __syncthreads();

    // ---- phase 2: m = relu(BN2(sMid @ W2 + b2)) -> staged into sIn ----
    {
        const bf16x8* base2 = (const bf16x8*)pW2;
#pragma unroll
        for (int jj = 0; jj < 2; jj++) {
            int nt = w * 2 + jj;
            f32x4 acc[2];
            acc[0] = (f32x4){0.f, 0.f, 0.f, 0.f};
            acc[1] = (f32x4){0.f, 0.f, 0.f, 0.f};
#pragma unroll
            for (int kh = 0; kh < 2; kh++) {
                bf16x8 b[4];
#pragma unroll
                for (int kt = 0; kt < 4; kt++)
                    b[kt] = base2[(size_t)(nt * 8 + kh * 4 + kt) * 64 + L];
#pragma unroll
                for (int hh = 0; hh < 2; hh++) {
                    int mh = hh * 16;
#pragma unroll
                    for (int kt = 0; kt < 4; kt++) {
                        bf16x8 a = *(const bf16x8*)&sMid[mh + l16][(kh * 4 + kt) * 32 + quad * 8];
                        acc[hh] = __builtin_amdgcn_mfma_f32_16x16x32_bf16(a, b[kt], acc[hh], 0, 0, 0);
                    }
                }
            }
            int c = nt * 16 + l16;
            float sc = g2[c] * rsqrtf(va2[c] + 1e-5f);
            float sh = (b2[c] - mu2[c]) * sc + be2[c];
#pragma unroll
            for (int hh = 0; hh < 2; hh++) {
#pragma unroll
                for (int r = 0; r < 4; r++) {
                    float o = fmaxf(acc[hh][r] * sc + sh, 0.f);
                    sIn[hh * 16 + quad * 4 + r][c] = f2bs(o);
                }
            }
        }
    }
    __syncthreads();

    // ---- coalesced epilogue: hb_out = hb_in + m (16 B/lane streams) ----
    {
        const u16x8* hs8 = (const u16x8*)hb_in;
#pragma unroll
        for (int idx = t; idx < 512; idx += 256) {
            int row = idx >> 4, seg = idx & 15;
            int node = node0 + row;
            if (node < n) {
                u16x8 m = *(const u16x8*)&sIn[row][seg * 8];
                u16x8 s = hs8[(size_t)node * 16 + seg];
                u16x8 o;
#pragma unroll
                for (int j = 0; j < 8; j++)
                    o[j] = f2bs(bs2f(s[j]) + bs2f(m[j]));
                *(u16x8*)(hb_out + (size_t)node * 128 + seg * 8) = o;
            }
        }
    }
}

// ---------------- pooling: run-length over sorted batch (bf16 in) ---------
// 16-node runs -> ~1563 blocks (~6/CU) so the serial load chain is short.
__global__ __launch_bounds__(256) void k_pool(const unsigned short* __restrict__ hb,
                                              const int* __restrict__ batch,
                                              float* __restrict__ pooled, int n)
{
    int c = threadIdx.x & 127;
    int half = threadIdx.x >> 7;
    int base = blockIdx.x * 32 + half * 16;
    float acc = 0.f;
    int curg = -1;
    for (int i = 0; i < 16; i++) {
        int node = base + i;
        if (node >= n) break;
        int g = batch[node];
        if (g != curg) {
            if (curg >= 0) atomicAdd(&pooled[(size_t)curg * 128 + c], acc);
            curg = g;
            acc = 0.f;
        }
        acc += bs2f(hb[(size_t)node * 128 + c]);
    }
    if (curg >= 0) atomicAdd(&pooled[(size_t)curg * 128 + c], acc);
}

__global__ __launch_bounds__(128) void k_head(const float* __restrict__ pooled,
                                              const float* __restrict__ W1,
                                              const float* __restrict__ b1,
                                              const float* __restrict__ W2,
                                              const float* __restrict__ b2,
                                              float* __restrict__ out)
{
    __shared__ float sp[128];
    __shared__ float st[128];
    int t = threadIdx.x;
    int g = blockIdx.x;
    sp[t] = pooled[(size_t)g * 128 + t];
    __syncthreads();
    float a = 0.f;
    for (int k = 0; k < 128; k++) a += sp[k] * W1[k * 128 + t];
    st[t] = fmaxf(a + b1[t], 0.f);
    __syncthreads();
    float o = 0.f;
    for (int k = 0; k < 128; k++) o += st[k] * W2[k * 128 + t];
    out[(size_t)g * 128 + t] = o + b2[t];
}

extern "C" void kernel_launch(void* const* d_in, const int* in_sizes, int n_in,
                              void* d_out, int out_size, void* d_ws, size_t ws_size,
                              hipStream_t stream)
{
    const float* x     = (const float*)d_in[0];
    const int*   ei    = (const int*)d_in[1];
    const int*   batch = (const int*)d_in[2];
    const float* W0    = (const float*)d_in[3];
    const float* b0    = (const float*)d_in[4];
    const float* mlpW1 = (const float*)d_in[5];
    const float* mlpb1 = (const float*)d_in[6];
    const float* bn1g  = (const float*)d_in[7];
    const float* bn1b  = (const float*)d_in[8];
    const float* bn1m  = (const float*)d_in[9];
    const float* bn1v  = (const float*)d_in[10];
    const float* mlpW2 = (const float*)d_in[11];
    const float* mlpb2 = (const float*)d_in[12];
    const float* ng    = (const float*)d_in[13];
    const float* nb    = (const float*)d_in[14];
    const float* nm    = (const float*)d_in[15];
    const float* nv    = (const float*)d_in[16];
    const float* W1    = (const float*)d_in[17];
    const float* b1    = (const float*)d_in[18];
    const float* W2    = (const float*)d_in[19];
    const float* b2    = (const float*)d_in[20];
    float* out = (float*)d_out;

    const int N = in_sizes[0] / 128;
    const int E = in_sizes[1] / 2;
    const int G = out_size / 128;
    const int* srcv = ei;
    const int* dstv = ei + E;

    // workspace layout
    float* pooled = (float*)d_ws;                               // G*128 f32
    unsigned short* hbA = (unsigned short*)(pooled + (size_t)G * 128); // N*128
    unsigned short* hbB = hbA + (size_t)N * 128;                // N*128
    short* pW1 = (short*)(hbB + (size_t)N * 128);               // 4*128*256
    short* pW2 = pW1 + 131072;                                  // 4*256*128
    short* pW0 = pW2 + 131072;                                  // 128*128
    int* ints  = (int*)(pW0 + 16384);
    int* deg      = ints;
    int* rowptr   = ints + N;
    int* cursor   = ints + 2 * N + 1;
    int* partials = ints + 3 * N + 1;                           // 256
    int* adj      = ints + 3 * N + 1 + 256;                     // E

    const int nodeBlocks = (N + 31) / 32;
    const int nbScan = (N + 255) / 256;
    const int eBlocks = (E + 255) / 256;
    const int packBlocks = (PK1 + PK2 + PK0 + 255) / 256;

    // ---- memsets up front (pooled only needed before k_pool) ----
    hipMemsetAsync(deg, 0, (size_t)N * sizeof(int), stream);
    hipMemsetAsync(pooled, 0, (size_t)G * 128 * sizeof(float), stream);

    // ---- CSR build + weight packing (merged) ----
    k_prep_a<<<eBlocks + packBlocks, 256, 0, stream>>>(
        dstv, deg, E, mlpW1, mlpW2, W0, pW1, pW2, pW0, eBlocks);
    k_scanA<<<nbScan, 256, 0, stream>>>(deg, partials, N);
    k_scanC<<<nbScan, 256, 0, stream>>>(deg, partials, rowptr, cursor, N, nbScan);
    // ---- CSR fill + encoder (merged) ----
    k_prep_b<<<eBlocks + nodeBlocks, 256, 0, stream>>>(
        srcv, dstv, cursor, adj, E, x, pW0, b0, hbA, N, eBlocks);

    // ---- layers: fused gather+MLP, ping-pong hbA/hbB ----
    unsigned short* hc = hbA;
    unsigned short* hn = hbB;
    for (int l = 0; l < 4; l++) {
        k_layer<<<nodeBlocks, 256, 0, stream>>>(
            hc, hn, rowptr, adj,
            pW1 + (size_t)l * 32768, mlpb1 + (size_t)l * 256,
            bn1g + (size_t)l * 256, bn1b + (size_t)l * 256,
            bn1m + (size_t)l * 256, bn1v + (size_t)l * 256,
            pW2 + (size_t)l * 32768, mlpb2 + (size_t)l * 128,
            ng + (size_t)l * 128, nb + (size_t)l * 128,
            nm + (size_t)l * 128, nv + (size_t)l * 128,
            N);
        unsigned short* tmp = hc; hc = hn; hn = tmp;
    }

    // ---- pool + head ----
    k_pool<<<(N + 31) / 32, 256, 0, stream>>>(hc, batch, pooled, N);
    k_head<<<G, 128, 0, stream>>>(pooled, W1, b1, W2, b2, out);
}

// Round 7
// 376.777 us; speedup vs baseline: 1.1521x; 1.1521x over previous
//
#include <hip/hip_runtime.h>
#include <hip/hip_bf16.h>

// ---------------------------------------------------------------------------
// GIN encoder. Residual stream in bf16 only (ping-pong A/B).
// Fused per-layer kernel (k_layer): gather + MLP + residual.
// Round 7: round-6 structure with ONE change: __launch_bounds__(256,5).
// Round 6's (256,6) made the allocator target ~40 VGPR; the 4-stream
// gather needs ~80 -> it spilled ~31MB/dispatch to scratch (WRITE_SIZE
// 12.5->43.7MB) and regressed 41->60.6us. (256,5) caps at 102 VGPR: the
// natural ~80-reg allocation fits (no spill) and 80 VGPR already allows
// 6 waves/SIMD, so occupancy = min(LDS 25.6KB -> 6 blocks, VGPR -> 6)
// = 6 blocks/CU = 24 gather waves (round 4 ran 41us at 16).
// ---------------------------------------------------------------------------

typedef short bf16x8 __attribute__((ext_vector_type(8)));
typedef unsigned short u16x8 __attribute__((ext_vector_type(8)));
typedef float f32x4 __attribute__((ext_vector_type(4)));

__device__ __forceinline__ float bs2f(unsigned short u) {
    return __uint_as_float(((unsigned)u) << 16);
}
__device__ __forceinline__ unsigned short f2bs(float f) {
    __hip_bfloat16 h = __float2bfloat16(f);
    return *reinterpret_cast<unsigned short*>(&h);
}

// masked packed unpack-accumulate: msk=~0u accumulates, 0u adds +0.0f
__device__ __forceinline__ void accm(float* acc, u16x8 v, unsigned msk) {
    union { u16x8 u; unsigned int w[4]; } cv;
    cv.u = v;
#pragma unroll
    for (int k = 0; k < 4; k++) {
        unsigned int d = cv.w[k] & msk;
        acc[2 * k]     += __uint_as_float(d << 16);
        acc[2 * k + 1] += __uint_as_float(d & 0xffff0000u);
    }
}

// ---------------- CSR scan kernels ----------------
__global__ __launch_bounds__(256) void k_scanA(const int* __restrict__ deg,
                                               int* __restrict__ partials, int n)
{
    int i = blockIdx.x * 256 + threadIdx.x;
    int v = (i < n) ? deg[i] : 0;
#pragma unroll
    for (int off = 32; off >= 1; off >>= 1) v += __shfl_down(v, off, 64);
    __shared__ int ws[4];
    int wave = threadIdx.x >> 6;
    if ((threadIdx.x & 63) == 0) ws[wave] = v;
    __syncthreads();
    if (threadIdx.x == 0)
        partials[blockIdx.x] = ws[0] + ws[1] + ws[2] + ws[3];
}

__global__ __launch_bounds__(256) void k_scanC(const int* __restrict__ deg,
                                               const int* __restrict__ partials,
                                               int* __restrict__ rowptr,
                                               int* __restrict__ cursor,
                                               int n, int nb)
{
    __shared__ int sp[256];
    __shared__ int s[256];
    int t = threadIdx.x;
    int pv = (t < nb) ? partials[t] : 0;
    sp[t] = pv;
    __syncthreads();
    for (int off = 1; off < 256; off <<= 1) {
        int u = (t >= off) ? sp[t - off] : 0;
        __syncthreads();
        sp[t] += u;
        __syncthreads();
    }
    int base = (blockIdx.x == 0) ? 0 : sp[blockIdx.x - 1];
    int i = blockIdx.x * 256 + t;
    int v = (i < n) ? deg[i] : 0;
    s[t] = v;
    __syncthreads();
    for (int off = 1; off < 256; off <<= 1) {
        int u = (t >= off) ? s[t - off] : 0;
        __syncthreads();
        s[t] += u;
        __syncthreads();
    }
    int inc = s[t];
    if (i < n) {
        int ex = base + inc - v;
        rowptr[i] = ex;
        cursor[i] = ex;
        if (i == n - 1) rowptr[n] = base + inc;
    }
}

// ---------------- weight packing helper ----------------
__device__ __forceinline__ void pack_one(const float* __restrict__ W,
                                         short* __restrict__ P,
                                         int id, int Kt, int Nt)
{
    int lane = id & 63;
    int t = id >> 6;
    int kt = t % Kt; t /= Kt;
    int nt = t % Nt; int l = t / Nt;
    int K = Kt * 32, N = Nt * 16;
    const float* Wl = W + (size_t)l * K * N;
    int n = nt * 16 + (lane & 15);
    int kbase = kt * 32 + (lane >> 4) * 8;
    bf16x8 v;
#pragma unroll
    for (int j = 0; j < 8; j++)
        v[j] = (short)f2bs(Wl[(size_t)(kbase + j) * N + n]);
    *(bf16x8*)(P + (size_t)id * 8) = v;
}

#define PK1 16384   // 4 layers * Nt16 * Kt4 * 64
#define PK2 16384   // 4 layers * Nt8  * Kt8 * 64
#define PK0 2048    // 1 layer  * Nt8  * Kt4 * 64

// ---------------- merged: edge histogram | weight packing ----------------
__global__ __launch_bounds__(256) void k_prep_a(
    const int* __restrict__ dst, int* __restrict__ deg, int nE,
    const float* __restrict__ mlpW1, const float* __restrict__ mlpW2,
    const float* __restrict__ W0,
    short* __restrict__ pW1, short* __restrict__ pW2, short* __restrict__ pW0,
    int histBlocks)
{
    if ((int)blockIdx.x < histBlocks) {
        int i = blockIdx.x * 256 + threadIdx.x;
        if (i < nE) atomicAdd(&deg[dst[i]], 1);
    } else {
        int id = (blockIdx.x - histBlocks) * 256 + threadIdx.x;
        if (id < PK1) {
            pack_one(mlpW1, pW1, id, 4, 16);
        } else if (id < PK1 + PK2) {
            pack_one(mlpW2, pW2, id - PK1, 8, 8);
        } else if (id < PK1 + PK2 + PK0) {
            pack_one(W0, pW0, id - PK1 - PK2, 4, 8);
        }
    }
}

// ---------------- merged: CSR fill | encoder ----------------
// encoder: hb = bf16(x@W0 + b0) via MFMA
__global__ __launch_bounds__(256) void k_prep_b(
    const int* __restrict__ src, const int* __restrict__ dst,
    int* __restrict__ cursor, int* __restrict__ adj, int nE,
    const float* __restrict__ x, const short* __restrict__ pW0,
    const float* __restrict__ b0, unsigned short* __restrict__ hb, int n,
    int fillBlocks)
{
    __shared__ unsigned short sX[32][136];
    if ((int)blockIdx.x < fillBlocks) {
        int i = blockIdx.x * 256 + threadIdx.x;
        if (i < nE) {
            int pos = atomicAdd(&cursor[dst[i]], 1);
            adj[pos] = src[i];
        }
        return;
    }
    const int t = threadIdx.x;
    const int w = t >> 6;
    const int L = t & 63;
    const int node0 = (blockIdx.x - fillBlocks) * 32;

    const float4* x4 = (const float4*)x;
    for (int i = t; i < 32 * 32; i += 256) {
        int m = i >> 5, cgi = i & 31;
        int node = node0 + m;
        float4 v = make_float4(0.f, 0.f, 0.f, 0.f);
        if (node < n) v = x4[(size_t)node * 32 + cgi];
        ushort4 p;
        p.x = f2bs(v.x); p.y = f2bs(v.y); p.z = f2bs(v.z); p.w = f2bs(v.w);
        *(ushort4*)&sX[m][cgi * 4] = p;
    }
    __syncthreads();

    const int quad = L >> 4;
    const int l16 = L & 15;
    const bf16x8* base = (const bf16x8*)pW0;

#pragma unroll
    for (int jj = 0; jj < 2; jj++) {
        int nt = w * 2 + jj;
        bf16x8 b[4];
#pragma unroll
        for (int kt = 0; kt < 4; kt++)
            b[kt] = base[(size_t)(nt * 4 + kt) * 64 + L];
        int c = nt * 16 + l16;
        float bc = b0[c];
#pragma unroll
        for (int hh = 0; hh < 2; hh++) {
            int mh = hh * 16;
            f32x4 acc = {0.f, 0.f, 0.f, 0.f};
#pragma unroll
            for (int kt = 0; kt < 4; kt++) {
                bf16x8 a = *(const bf16x8*)&sX[mh + l16][kt * 32 + quad * 8];
                acc = __builtin_amdgcn_mfma_f32_16x16x32_bf16(a, b[kt], acc, 0, 0, 0);
            }
#pragma unroll
            for (int r = 0; r < 4; r++) {
                int node = node0 + mh + quad * 4 + r;
                if (node < n)
                    hb[(size_t)node * 128 + c] = f2bs(acc[r] + bc);
            }
        }
    }
}

// ---------------- fused layer: gather + MLP + residual --------------------
// hb_out = hb_in + relu(BN2(W2 relu(BN1(W1 (hb_in + sum_neighbors)))))
// Gather: 4 static streams/wave (rows ep*4+{0..3}) x 2 episodes, clamped+
// masked 4-edge chunks (unroll-2 per stream), adj prefetched one chunk
// ahead. Lane layout: g = L>>4 picks 1 of 4 edges in the chunk, l16 = L&15
// is the 16B channel segment; 16 lanes cover one 256B node row.
// launch_bounds(256,5): VGPR cap 102 fits the natural ~80-reg allocation
// (no spill); 80 VGPR allows 6 waves/SIMD, so LDS (25.6KB) sets the cap
// at 6 blocks/CU.
__global__ __launch_bounds__(256, 5) void k_layer(
    const unsigned short* __restrict__ hb_in,
    unsigned short* __restrict__ hb_out,
    const int* __restrict__ rowptr, const int* __restrict__ adj,
    const short* __restrict__ pW1, const float* __restrict__ b1,
    const float* __restrict__ g1, const float* __restrict__ be1,
    const float* __restrict__ mu1, const float* __restrict__ va1,
    const short* __restrict__ pW2, const float* __restrict__ b2,
    const float* __restrict__ g2, const float* __restrict__ be2,
    const float* __restrict__ mu2, const float* __restrict__ va2,
    int n)
{
    __shared__ unsigned short sIn[32][136];    // gathered agg; reused for m out
    __shared__ unsigned short sMid[32][264];   // bf16 MLP hidden, pad 8
    const int t = threadIdx.x;
    const int w = t >> 6;
    const int L = t & 63;
    const int node0 = blockIdx.x * 32;
    const int g = L >> 4;
    const int l16 = L & 15;
    const int wrow = w * 8;

    // ---- gather phase: wave w fills sIn rows wrow..wrow+7 ----
    {
        const u16x8* hb8 = (const u16x8*)hb_in;
        const int base = node0 + wrow;

        // rowptr[base .. base+8], index-clamped so OOB rows degenerate
        // to empty ranges (rowptr[n] repeated).
        int rp[9];
#pragma unroll
        for (int j = 0; j < 9; j++) {
            int idx = base + j;
            rp[j] = rowptr[idx > n ? n : idx];
        }

#define CHUNK_INIT(S, EE, QQ)                                               \
        int e##S = (EE), q##S = (QQ);                                       \
        bool ok##S = e##S < q##S;                                           \
        int x##S##0 = e##S + g, x##S##1 = e##S + 4 + g;                     \
        int i##S##0 = adj[ok##S ? (x##S##0 < q##S ? x##S##0 : q##S - 1) : 0]; \
        int i##S##1 = adj[ok##S ? (x##S##1 < q##S ? x##S##1 : q##S - 1) : 0]; \
        float acc##S[8] = {0.f,0.f,0.f,0.f,0.f,0.f,0.f,0.f};

#define CHUNK_LOAD(S)                                                       \
        u16x8 r##S##0 = hb8[(unsigned)i##S##0 * 16u + l16];                 \
        u16x8 r##S##1 = hb8[(unsigned)i##S##1 * 16u + l16];

#define CHUNK_MASK(S)                                                       \
        unsigned m##S##0 = (ok##S && e##S + g < q##S)     ? ~0u : 0u;       \
        unsigned m##S##1 = (ok##S && e##S + 4 + g < q##S) ? ~0u : 0u;

#define CHUNK_PREF(S)                                                       \
        int ne##S = ok##S ? e##S + 8 : e##S;                                \
        bool nok##S = ne##S < q##S;                                         \
        int nx##S##0 = ne##S + g, nx##S##1 = ne##S + 4 + g;                 \
        int ni##S##0 = adj[nok##S ? (nx##S##0 < q##S ? nx##S##0 : q##S - 1) : 0]; \
        int ni##S##1 = adj[nok##S ? (nx##S##1 < q##S ? nx##S##1 : q##S - 1) : 0];

#define CHUNK_ACC(S)                                                        \
        accm(acc##S, r##S##0, m##S##0);                                     \
        accm(acc##S, r##S##1, m##S##1);

#define CHUNK_ROT(S)                                                        \
        e##S = ne##S; ok##S = nok##S; i##S##0 = ni##S##0; i##S##1 = ni##S##1;

#define SELF_LOAD(S, NODE)                                                  \
        u16x8 self##S;                                                      \
        {                                                                   \
            _Pragma("unroll")                                               \
            for (int j = 0; j < 8; j++) self##S[j] = 0;                     \
            if ((NODE) < n) self##S = hb8[(unsigned)(NODE) * 16u + l16];    \
        }

#define STREAM_FIN(S, ROWIDX)                                               \
        {                                                                   \
            u16x8 o;                                                        \
            _Pragma("unroll")                                               \
            for (int j = 0; j < 8; j++) {                                   \
                float vv = acc##S[j];                                       \
                vv += __shfl_xor(vv, 16, 64);                               \
                vv += __shfl_xor(vv, 32, 64);                               \
                o[j] = f2bs(vv + bs2f(self##S[j]));                         \
            }                                                               \
            if (g == 0) *(u16x8*)&sIn[(ROWIDX)][l16 * 8] = o;               \
        }

#pragma unroll
        for (int ep = 0; ep < 2; ep++) {
            const int r0 = ep * 4;
            CHUNK_INIT(A, rp[r0 + 0], rp[r0 + 1])
            CHUNK_INIT(B, rp[r0 + 1], rp[r0 + 2])
            CHUNK_INIT(C, rp[r0 + 2], rp[r0 + 3])
            CHUNK_INIT(D, rp[r0 + 3], rp[r0 + 4])

            while (okA | okB | okC | okD) {
                CHUNK_LOAD(A) CHUNK_LOAD(B) CHUNK_LOAD(C) CHUNK_LOAD(D)
                CHUNK_MASK(A) CHUNK_MASK(B) CHUNK_MASK(C) CHUNK_MASK(D)
                CHUNK_PREF(A) CHUNK_PREF(B) CHUNK_PREF(C) CHUNK_PREF(D)
                CHUNK_ACC(A) CHUNK_ACC(B) CHUNK_ACC(C) CHUNK_ACC(D)
                CHUNK_ROT(A) CHUNK_ROT(B) CHUNK_ROT(C) CHUNK_ROT(D)
            }

            SELF_LOAD(A, base + r0 + 0)
            SELF_LOAD(B, base + r0 + 1)
            SELF_LOAD(C, base + r0 + 2)
            SELF_LOAD(D, base + r0 + 3)
            STREAM_FIN(A, wrow + r0 + 0)
            STREAM_FIN(B, wrow + r0 + 1)
            STREAM_FIN(C, wrow + r0 + 2)
            STREAM_FIN(D, wrow + r0 + 3)
        }
#undef CHUNK_INIT
#undef CHUNK_LOAD
#undef CHUNK_MASK
#undef CHUNK_PREF
#undef CHUNK_ACC
#undef CHUNK_ROT
#undef SELF_LOAD
#undef STREAM_FIN
    }
    __syncthreads();

    const int quad = L >> 4;

    // ---- phase 1: sMid = relu(BN1(sIn @ W1 + b1)), 32x256, K=128 ----
    {
        const bf16x8* base1 = (const bf16x8*)pW1;
#pragma unroll
        for (int j = 0; j < 4; j++) {
            int nt = w * 4 + j;
            bf16x8 b[4];
#pragma unroll
            for (int kt = 0; kt < 4; kt++)
                b[kt] = base1[(size_t)(nt * 4 + kt) * 64 + L];
            int c = nt * 16 + l16;
            float sc = g1[c] * rsqrtf(va1[c] + 1e-5f);
            float sh = (b1[c] - mu1[c]) * sc + be1[c];
#pragma unroll
            for (int hh = 0; hh < 2; hh++) {
                int mh = hh * 16;
                f32x4 acc = {0.f, 0.f, 0.f, 0.f};
#pragma unroll
                for (int kt = 0; kt < 4; kt++) {
                    bf16x8 a = *(const bf16x8*)&sIn[mh + l16][kt * 32 + quad * 8];
                    acc = __builtin_amdgcn_mfma_f32_16x16x32_bf16(a, b[kt], acc, 0, 0, 0);
                }
#pragma unroll
                for (int r = 0; r < 4; r++) {
                    float v = fmaxf(acc[r] * sc + sh, 0.f);
                    sMid[mh + quad * 4 + r][c] = f2bs(v);
                }
            }
        }
    }
    __syncthreads();

    // ---- phase 2: m = relu(BN2(sMid @ W2 + b2)) -> staged into sIn ----
    {
        const bf16x8* base2 = (const bf16x8*)pW2;
#pragma unroll
        for (int jj = 0; jj < 2; jj++) {
            int nt = w * 2 + jj;
            f32x4 acc[2];
            acc[0] = (f32x4){0.f, 0.f, 0.f, 0.f};
            acc[1] = (f32x4){0.f, 0.f, 0.f, 0.f};
#pragma unroll
            for (int kh = 0; kh < 2; kh++) {
                bf16x8 b[4];
#pragma unroll
                for (int kt = 0; kt < 4; kt++)
                    b[kt] = base2[(size_t)(nt * 8 + kh * 4 + kt) * 64 + L];
#pragma unroll
                for (int hh = 0; hh < 2; hh++) {
                    int mh = hh * 16;
#pragma unroll
                    for (int kt = 0; kt < 4; kt++) {
                        bf16x8 a = *(const bf16x8*)&sMid[mh + l16][(kh * 4 + kt) * 32 + quad * 8];
                        acc[hh] = __builtin_amdgcn_mfma_f32_16x16x32_bf16(a, b[kt], acc[hh], 0, 0, 0);
                    }
                }
            }
            int c = nt * 16 + l16;
            float sc = g2[c] * rsqrtf(va2[c] + 1e-5f);
            float sh = (b2[c] - mu2[c]) * sc + be2[c];
#pragma unroll
            for (int hh = 0; hh < 2; hh++) {
#pragma unroll
                for (int r = 0; r < 4; r++) {
                    float o = fmaxf(acc[hh][r] * sc + sh, 0.f);
                    sIn[hh * 16 + quad * 4 + r][c] = f2bs(o);
                }
            }
        }
    }
    __syncthreads();

    // ---- coalesced epilogue: hb_out = hb_in + m (16 B/lane streams) ----
    {
        const u16x8* hs8 = (const u16x8*)hb_in;
#pragma unroll
        for (int idx = t; idx < 512; idx += 256) {
            int row = idx >> 4, seg = idx & 15;
            int node = node0 + row;
            if (node < n) {
                u16x8 m = *(const u16x8*)&sIn[row][seg * 8];
                u16x8 s = hs8[(size_t)node * 16 + seg];
                u16x8 o;
#pragma unroll
                for (int j = 0; j < 8; j++)
                    o[j] = f2bs(bs2f(s[j]) + bs2f(m[j]));
                *(u16x8*)(hb_out + (size_t)node * 128 + seg * 8) = o;
            }
        }
    }
}

// ---------------- pooling: run-length over sorted batch (bf16 in) ---------
// 16-node runs -> ~1563 blocks (~6/CU) so the serial load chain is short.
__global__ __launch_bounds__(256) void k_pool(const unsigned short* __restrict__ hb,
                                              const int* __restrict__ batch,
                                              float* __restrict__ pooled, int n)
{
    int c = threadIdx.x & 127;
    int half = threadIdx.x >> 7;
    int base = blockIdx.x * 32 + half * 16;
    float acc = 0.f;
    int curg = -1;
    for (int i = 0; i < 16; i++) {
        int node = base + i;
        if (node >= n) break;
        int g = batch[node];
        if (g != curg) {
            if (curg >= 0) atomicAdd(&pooled[(size_t)curg * 128 + c], acc);
            curg = g;
            acc = 0.f;
        }
        acc += bs2f(hb[(size_t)node * 128 + c]);
    }
    if (curg >= 0) atomicAdd(&pooled[(size_t)curg * 128 + c], acc);
}

__global__ __launch_bounds__(128) void k_head(const float* __restrict__ pooled,
                                              const float* __restrict__ W1,
                                              const float* __restrict__ b1,
                                              const float* __restrict__ W2,
                                              const float* __restrict__ b2,
                                              float* __restrict__ out)
{
    __shared__ float sp[128];
    __shared__ float st[128];
    int t = threadIdx.x;
    int g = blockIdx.x;
    sp[t] = pooled[(size_t)g * 128 + t];
    __syncthreads();
    float a = 0.f;
    for (int k = 0; k < 128; k++) a += sp[k] * W1[k * 128 + t];
    st[t] = fmaxf(a + b1[t], 0.f);
    __syncthreads();
    float o = 0.f;
    for (int k = 0; k < 128; k++) o += st[k] * W2[k * 128 + t];
    out[(size_t)g * 128 + t] = o + b2[t];
}

extern "C" void kernel_launch(void* const* d_in, const int* in_sizes, int n_in,
                              void* d_out, int out_size, void* d_ws, size_t ws_size,
                              hipStream_t stream)
{
    const float* x     = (const float*)d_in[0];
    const int*   ei    = (const int*)d_in[1];
    const int*   batch = (const int*)d_in[2];
    const float* W0    = (const float*)d_in[3];
    const float* b0    = (const float*)d_in[4];
    const float* mlpW1 = (const float*)d_in[5];
    const float* mlpb1 = (const float*)d_in[6];
    const float* bn1g  = (const float*)d_in[7];
    const float* bn1b  = (const float*)d_in[8];
    const float* bn1m  = (const float*)d_in[9];
    const float* bn1v  = (const float*)d_in[10];
    const float* mlpW2 = (const float*)d_in[11];
    const float* mlpb2 = (const float*)d_in[12];
    const float* ng    = (const float*)d_in[13];
    const float* nb    = (const float*)d_in[14];
    const float* nm    = (const float*)d_in[15];
    const float* nv    = (const float*)d_in[16];
    const float* W1    = (const float*)d_in[17];
    const float* b1    = (const float*)d_in[18];
    const float* W2    = (const float*)d_in[19];
    const float* b2    = (const float*)d_in[20];
    float* out = (float*)d_out;

    const int N = in_sizes[0] / 128;
    const int E = in_sizes[1] / 2;
    const int G = out_size / 128;
    const int* srcv = ei;
    const int* dstv = ei + E;

    // workspace layout
    float* pooled = (float*)d_ws;                               // G*128 f32
    unsigned short* hbA = (unsigned short*)(pooled + (size_t)G * 128); // N*128
    unsigned short* hbB = hbA + (size_t)N * 128;                // N*128
    short* pW1 = (short*)(hbB + (size_t)N * 128);               // 4*128*256
    short* pW2 = pW1 + 131072;                                  // 4*256*128
    short* pW0 = pW2 + 131072;                                  // 128*128
    int* ints  = (int*)(pW0 + 16384);
    int* deg      = ints;
    int* rowptr   = ints + N;
    int* cursor   = ints + 2 * N + 1;
    int* partials = ints + 3 * N + 1;                           // 256
    int* adj      = ints + 3 * N + 1 + 256;                     // E

    const int nodeBlocks = (N + 31) / 32;
    const int nbScan = (N + 255) / 256;
    const int eBlocks = (E + 255) / 256;
    const int packBlocks = (PK1 + PK2 + PK0 + 255) / 256;

    // ---- memsets up front (pooled only needed before k_pool) ----
    hipMemsetAsync(deg, 0, (size_t)N * sizeof(int), stream);
    hipMemsetAsync(pooled, 0, (size_t)G * 128 * sizeof(float), stream);

    // ---- CSR build + weight packing (merged) ----
    k_prep_a<<<eBlocks + packBlocks, 256, 0, stream>>>(
        dstv, deg, E, mlpW1, mlpW2, W0, pW1, pW2, pW0, eBlocks);
    k_scanA<<<nbScan, 256, 0, stream>>>(deg, partials, N);
    k_scanC<<<nbScan, 256, 0, stream>>>(deg, partials, rowptr, cursor, N, nbScan);
    // ---- CSR fill + encoder (merged) ----
    k_prep_b<<<eBlocks + nodeBlocks, 256, 0, stream>>>(
        srcv, dstv, cursor, adj, E, x, pW0, b0, hbA, N, eBlocks);

    // ---- layers: fused gather+MLP, ping-pong hbA/hbB ----
    unsigned short* hc = hbA;
    unsigned short* hn = hbB;
    for (int l = 0; l < 4; l++) {
        k_layer<<<nodeBlocks, 256, 0, stream>>>(
            hc, hn, rowptr, adj,
            pW1 + (size_t)l * 32768, mlpb1 + (size_t)l * 256,
            bn1g + (size_t)l * 256, bn1b + (size_t)l * 256,
            bn1m + (size_t)l * 256, bn1v + (size_t)l * 256,
            pW2 + (size_t)l * 32768, mlpb2 + (size_t)l * 128,
            ng + (size_t)l * 128, nb + (size_t)l * 128,
            nm + (size_t)l * 128, nv + (size_t)l * 128,
            N);
        unsigned short* tmp = hc; hc = hn; hn = tmp;
    }

    // ---- pool + head ----
    k_pool<<<(N + 31) / 32, 256, 0, stream>>>(hc, batch, pooled, N);
    k_head<<<G, 128, 0, stream>>>(pooled, W1, b1, W2, b2, out);
}

// Round 8
// 354.045 us; speedup vs baseline: 1.2261x; 1.0642x over previous
//
#include <hip/hip_runtime.h>
#include <hip/hip_bf16.h>

// ---------------------------------------------------------------------------
// GIN encoder. Residual stream in bf16 only (ping-pong A/B).
// Fused per-layer kernel (k_layer): gather + MLP + residual.
// Round 8: round-7 kernel with __launch_bounds__(256,4).
// Allocator calibration from R4-R7: natural gather footprint is 80 VGPR.
//   (256,6) -> forced 40 VGPR, 31MB spill, 60.6us (R6)
//   (256,5) -> forced 48 VGPR, 1.5MB spill, 48us  (R7)
//   (256,4)/(256,3) -> natural 80 VGPR, no spill  (R4/R5)
// With no sSelf the LDS is 25.6KB -> 6.25 blocks/CU, and 80 VGPR allows
// 6 waves/SIMD, so actual occupancy = 6 blocks/CU (vs R4's LDS-capped 4)
// with R4's exact no-spill per-wave code.
// ---------------------------------------------------------------------------

typedef short bf16x8 __attribute__((ext_vector_type(8)));
typedef unsigned short u16x8 __attribute__((ext_vector_type(8)));
typedef float f32x4 __attribute__((ext_vector_type(4)));

__device__ __forceinline__ float bs2f(unsigned short u) {
    return __uint_as_float(((unsigned)u) << 16);
}
__device__ __forceinline__ unsigned short f2bs(float f) {
    __hip_bfloat16 h = __float2bfloat16(f);
    return *reinterpret_cast<unsigned short*>(&h);
}

// masked packed unpack-accumulate: msk=~0u accumulates, 0u adds +0.0f
__device__ __forceinline__ void accm(float* acc, u16x8 v, unsigned msk) {
    union { u16x8 u; unsigned int w[4]; } cv;
    cv.u = v;
#pragma unroll
    for (int k = 0; k < 4; k++) {
        unsigned int d = cv.w[k] & msk;
        acc[2 * k]     += __uint_as_float(d << 16);
        acc[2 * k + 1] += __uint_as_float(d & 0xffff0000u);
    }
}

// ---------------- CSR scan kernels ----------------
__global__ __launch_bounds__(256) void k_scanA(const int* __restrict__ deg,
                                               int* __restrict__ partials, int n)
{
    int i = blockIdx.x * 256 + threadIdx.x;
    int v = (i < n) ? deg[i] : 0;
#pragma unroll
    for (int off = 32; off >= 1; off >>= 1) v += __shfl_down(v, off, 64);
    __shared__ int ws[4];
    int wave = threadIdx.x >> 6;
    if ((threadIdx.x & 63) == 0) ws[wave] = v;
    __syncthreads();
    if (threadIdx.x == 0)
        partials[blockIdx.x] = ws[0] + ws[1] + ws[2] + ws[3];
}

__global__ __launch_bounds__(256) void k_scanC(const int* __restrict__ deg,
                                               const int* __restrict__ partials,
                                               int* __restrict__ rowptr,
                                               int* __restrict__ cursor,
                                               int n, int nb)
{
    __shared__ int sp[256];
    __shared__ int s[256];
    int t = threadIdx.x;
    int pv = (t < nb) ? partials[t] : 0;
    sp[t] = pv;
    __syncthreads();
    for (int off = 1; off < 256; off <<= 1) {
        int u = (t >= off) ? sp[t - off] : 0;
        __syncthreads();
        sp[t] += u;
        __syncthreads();
    }
    int base = (blockIdx.x == 0) ? 0 : sp[blockIdx.x - 1];
    int i = blockIdx.x * 256 + t;
    int v = (i < n) ? deg[i] : 0;
    s[t] = v;
    __syncthreads();
    for (int off = 1; off < 256; off <<= 1) {
        int u = (t >= off) ? s[t - off] : 0;
        __syncthreads();
        s[t] += u;
        __syncthreads();
    }
    int inc = s[t];
    if (i < n) {
        int ex = base + inc - v;
        rowptr[i] = ex;
        cursor[i] = ex;
        if (i == n - 1) rowptr[n] = base + inc;
    }
}

// ---------------- weight packing helper ----------------
__device__ __forceinline__ void pack_one(const float* __restrict__ W,
                                         short* __restrict__ P,
                                         int id, int Kt, int Nt)
{
    int lane = id & 63;
    int t = id >> 6;
    int kt = t % Kt; t /= Kt;
    int nt = t % Nt; int l = t / Nt;
    int K = Kt * 32, N = Nt * 16;
    const float* Wl = W + (size_t)l * K * N;
    int n = nt * 16 + (lane & 15);
    int kbase = kt * 32 + (lane >> 4) * 8;
    bf16x8 v;
#pragma unroll
    for (int j = 0; j < 8; j++)
        v[j] = (short)f2bs(Wl[(size_t)(kbase + j) * N + n]);
    *(bf16x8*)(P + (size_t)id * 8) = v;
}

#define PK1 16384   // 4 layers * Nt16 * Kt4 * 64
#define PK2 16384   // 4 layers * Nt8  * Kt8 * 64
#define PK0 2048    // 1 layer  * Nt8  * Kt4 * 64

// ---------------- merged: edge histogram | weight packing ----------------
__global__ __launch_bounds__(256) void k_prep_a(
    const int* __restrict__ dst, int* __restrict__ deg, int nE,
    const float* __restrict__ mlpW1, const float* __restrict__ mlpW2,
    const float* __restrict__ W0,
    short* __restrict__ pW1, short* __restrict__ pW2, short* __restrict__ pW0,
    int histBlocks)
{
    if ((int)blockIdx.x < histBlocks) {
        int i = blockIdx.x * 256 + threadIdx.x;
        if (i < nE) atomicAdd(&deg[dst[i]], 1);
    } else {
        int id = (blockIdx.x - histBlocks) * 256 + threadIdx.x;
        if (id < PK1) {
            pack_one(mlpW1, pW1, id, 4, 16);
        } else if (id < PK1 + PK2) {
            pack_one(mlpW2, pW2, id - PK1, 8, 8);
        } else if (id < PK1 + PK2 + PK0) {
            pack_one(W0, pW0, id - PK1 - PK2, 4, 8);
        }
    }
}

// ---------------- merged: CSR fill | encoder ----------------
// encoder: hb = bf16(x@W0 + b0) via MFMA
__global__ __launch_bounds__(256) void k_prep_b(
    const int* __restrict__ src, const int* __restrict__ dst,
    int* __restrict__ cursor, int* __restrict__ adj, int nE,
    const float* __restrict__ x, const short* __restrict__ pW0,
    const float* __restrict__ b0, unsigned short* __restrict__ hb, int n,
    int fillBlocks)
{
    __shared__ unsigned short sX[32][136];
    if ((int)blockIdx.x < fillBlocks) {
        int i = blockIdx.x * 256 + threadIdx.x;
        if (i < nE) {
            int pos = atomicAdd(&cursor[dst[i]], 1);
            adj[pos] = src[i];
        }
        return;
    }
    const int t = threadIdx.x;
    const int w = t >> 6;
    const int L = t & 63;
    const int node0 = (blockIdx.x - fillBlocks) * 32;

    const float4* x4 = (const float4*)x;
    for (int i = t; i < 32 * 32; i += 256) {
        int m = i >> 5, cgi = i & 31;
        int node = node0 + m;
        float4 v = make_float4(0.f, 0.f, 0.f, 0.f);
        if (node < n) v = x4[(size_t)node * 32 + cgi];
        ushort4 p;
        p.x = f2bs(v.x); p.y = f2bs(v.y); p.z = f2bs(v.z); p.w = f2bs(v.w);
        *(ushort4*)&sX[m][cgi * 4] = p;
    }
    __syncthreads();

    const int quad = L >> 4;
    const int l16 = L & 15;
    const bf16x8* base = (const bf16x8*)pW0;

#pragma unroll
    for (int jj = 0; jj < 2; jj++) {
        int nt = w * 2 + jj;
        bf16x8 b[4];
#pragma unroll
        for (int kt = 0; kt < 4; kt++)
            b[kt] = base[(size_t)(nt * 4 + kt) * 64 + L];
        int c = nt * 16 + l16;
        float bc = b0[c];
#pragma unroll
        for (int hh = 0; hh < 2; hh++) {
            int mh = hh * 16;
            f32x4 acc = {0.f, 0.f, 0.f, 0.f};
#pragma unroll
            for (int kt = 0; kt < 4; kt++) {
                bf16x8 a = *(const bf16x8*)&sX[mh + l16][kt * 32 + quad * 8];
                acc = __builtin_amdgcn_mfma_f32_16x16x32_bf16(a, b[kt], acc, 0, 0, 0);
            }
#pragma unroll
            for (int r = 0; r < 4; r++) {
                int node = node0 + mh + quad * 4 + r;
                if (node < n)
                    hb[(size_t)node * 128 + c] = f2bs(acc[r] + bc);
            }
        }
    }
}

// ---------------- fused layer: gather + MLP + residual --------------------
// hb_out = hb_in + relu(BN2(W2 relu(BN1(W1 (hb_in + sum_neighbors)))))
// Gather: 4 static streams/wave (rows ep*4+{0..3}) x 2 episodes, clamped+
// masked 4-edge chunks (unroll-2 per stream), adj prefetched one chunk
// ahead. Lane layout: g = L>>4 picks 1 of 4 edges in the chunk, l16 = L&15
// is the 16B channel segment; 16 lanes cover one 256B node row.
// launch_bounds(256,4): 128-VGPR ceiling, allocator settles at natural ~80
// with no spill (R4/R5); actual occupancy = min(LDS 25.6KB -> 6 blocks,
// 80 VGPR -> 6 waves/SIMD) = 6 blocks/CU.
__global__ __launch_bounds__(256, 4) void k_layer(
    const unsigned short* __restrict__ hb_in,
    unsigned short* __restrict__ hb_out,
    const int* __restrict__ rowptr, const int* __restrict__ adj,
    const short* __restrict__ pW1, const float* __restrict__ b1,
    const float* __restrict__ g1, const float* __restrict__ be1,
    const float* __restrict__ mu1, const float* __restrict__ va1,
    const short* __restrict__ pW2, const float* __restrict__ b2,
    const float* __restrict__ g2, const float* __restrict__ be2,
    const float* __restrict__ mu2, const float* __restrict__ va2,
    int n)
{
    __shared__ unsigned short sIn[32][136];    // gathered agg; reused for m out
    __shared__ unsigned short sMid[32][264];   // bf16 MLP hidden, pad 8
    const int t = threadIdx.x;
    const int w = t >> 6;
    const int L = t & 63;
    const int node0 = blockIdx.x * 32;
    const int g = L >> 4;
    const int l16 = L & 15;
    const int wrow = w * 8;

    // ---- gather phase: wave w fills sIn rows wrow..wrow+7 ----
    {
        const u16x8* hb8 = (const u16x8*)hb_in;
        const int base = node0 + wrow;

        // rowptr[base .. base+8], index-clamped so OOB rows degenerate
        // to empty ranges (rowptr[n] repeated).
        int rp[9];
#pragma unroll
        for (int j = 0; j < 9; j++) {
            int idx = base + j;
            rp[j] = rowptr[idx > n ? n : idx];
        }

#define CHUNK_INIT(S, EE, QQ)                                               \
        int e##S = (EE), q##S = (QQ);                                       \
        bool ok##S = e##S < q##S;                                           \
        int x##S##0 = e##S + g, x##S##1 = e##S + 4 + g;                     \
        int i##S##0 = adj[ok##S ? (x##S##0 < q##S ? x##S##0 : q##S - 1) : 0]; \
        int i##S##1 = adj[ok##S ? (x##S##1 < q##S ? x##S##1 : q##S - 1) : 0]; \
        float acc##S[8] = {0.f,0.f,0.f,0.f,0.f,0.f,0.f,0.f};

#define CHUNK_LOAD(S)                                                       \
        u16x8 r##S##0 = hb8[(unsigned)i##S##0 * 16u + l16];                 \
        u16x8 r##S##1 = hb8[(unsigned)i##S##1 * 16u + l16];

#define CHUNK_MASK(S)                                                       \
        unsigned m##S##0 = (ok##S && e##S + g < q##S)     ? ~0u : 0u;       \
        unsigned m##S##1 = (ok##S && e##S + 4 + g < q##S) ? ~0u : 0u;

#define CHUNK_PREF(S)                                                       \
        int ne##S = ok##S ? e##S + 8 : e##S;                                \
        bool nok##S = ne##S < q##S;                                         \
        int nx##S##0 = ne##S + g, nx##S##1 = ne##S + 4 + g;                 \
        int ni##S##0 = adj[nok##S ? (nx##S##0 < q##S ? nx##S##0 : q##S - 1) : 0]; \
        int ni##S##1 = adj[nok##S ? (nx##S##1 < q##S ? nx##S##1 : q##S - 1) : 0];

#define CHUNK_ACC(S)                                                        \
        accm(acc##S, r##S##0, m##S##0);                                     \
        accm(acc##S, r##S##1, m##S##1);

#define CHUNK_ROT(S)                                                        \
        e##S = ne##S; ok##S = nok##S; i##S##0 = ni##S##0; i##S##1 = ni##S##1;

#define SELF_LOAD(S, NODE)                                                  \
        u16x8 self##S;                                                      \
        {                                                                   \
            _Pragma("unroll")                                               \
            for (int j = 0; j < 8; j++) self##S[j] = 0;                     \
            if ((NODE) < n) self##S = hb8[(unsigned)(NODE) * 16u + l16];    \
        }

#define STREAM_FIN(S, ROWIDX)                                               \
        {                                                                   \
            u16x8 o;                                                        \
            _Pragma("unroll")                                               \
            for (int j = 0; j < 8; j++) {                                   \
                float vv = acc##S[j];                                       \
                vv += __shfl_xor(vv, 16, 64);                               \
                vv += __shfl_xor(vv, 32, 64);                               \
                o[j] = f2bs(vv + bs2f(self##S[j]));                         \
            }                                                               \
            if (g == 0) *(u16x8*)&sIn[(ROWIDX)][l16 * 8] = o;               \
        }

#pragma unroll
        for (int ep = 0; ep < 2; ep++) {
            const int r0 = ep * 4;
            CHUNK_INIT(A, rp[r0 + 0], rp[r0 + 1])
            CHUNK_INIT(B, rp[r0 + 1], rp[r0 + 2])
            CHUNK_INIT(C, rp[r0 + 2], rp[r0 + 3])
            CHUNK_INIT(D, rp[r0 + 3], rp[r0 + 4])

            while (okA | okB | okC | okD) {
                CHUNK_LOAD(A) CHUNK_LOAD(B) CHUNK_LOAD(C) CHUNK_LOAD(D)
                CHUNK_MASK(A) CHUNK_MASK(B) CHUNK_MASK(C) CHUNK_MASK(D)
                CHUNK_PREF(A) CHUNK_PREF(B) CHUNK_PREF(C) CHUNK_PREF(D)
                CHUNK_ACC(A) CHUNK_ACC(B) CHUNK_ACC(C) CHUNK_ACC(D)
                CHUNK_ROT(A) CHUNK_ROT(B) CHUNK_ROT(C) CHUNK_ROT(D)
            }

            SELF_LOAD(A, base + r0 + 0)
            SELF_LOAD(B, base + r0 + 1)
            SELF_LOAD(C, base + r0 + 2)
            SELF_LOAD(D, base + r0 + 3)
            STREAM_FIN(A, wrow + r0 + 0)
            STREAM_FIN(B, wrow + r0 + 1)
            STREAM_FIN(C, wrow + r0 + 2)
            STREAM_FIN(D, wrow + r0 + 3)
        }
#undef CHUNK_INIT
#undef CHUNK_LOAD
#undef CHUNK_MASK
#undef CHUNK_PREF
#undef CHUNK_ACC
#undef CHUNK_ROT
#undef SELF_LOAD
#undef STREAM_FIN
    }
    __syncthreads();

    const int quad = L >> 4;

    // ---- phase 1: sMid = relu(BN1(sIn @ W1 + b1)), 32x256, K=128 ----
    {
        const bf16x8* base1 = (const bf16x8*)pW1;
#pragma unroll
        for (int j = 0; j < 4; j++) {
            int nt = w * 4 + j;
            bf16x8 b[4];
#pragma unroll
            for (int kt = 0; kt < 4; kt++)
                b[kt] = base1[(size_t)(nt * 4 + kt) * 64 + L];
            int c = nt * 16 + l16;
            float sc = g1[c] * rsqrtf(va1[c] + 1e-5f);
            float sh = (b1[c] - mu1[c]) * sc + be1[c];
#pragma unroll
            for (int hh = 0; hh < 2; hh++) {
                int mh = hh * 16;
                f32x4 acc = {0.f, 0.f, 0.f, 0.f};
#pragma unroll
                for (int kt = 0; kt < 4; kt++) {
                    bf16x8 a = *(const bf16x8*)&sIn[mh + l16][kt * 32 + quad * 8];
                    acc = __builtin_amdgcn_mfma_f32_16x16x32_bf16(a, b[kt], acc, 0, 0, 0);
                }
#pragma unroll
                for (int r = 0; r < 4; r++) {
                    float v = fmaxf(acc[r] * sc + sh, 0.f);
                    sMid[mh + quad * 4 + r][c] = f2bs(v);
                }
            }
        }
    }
    __syncthreads();

    // ---- phase 2: m = relu(BN2(sMid @ W2 + b2)) -> staged into sIn ----
    {
        const bf16x8* base2 = (const bf16x8*)pW2;
#pragma unroll
        for (int jj = 0; jj < 2; jj++) {
            int nt = w * 2 + jj;
            f32x4 acc[2];
            acc[0] = (f32x4){0.f, 0.f, 0.f, 0.f};
            acc[1] = (f32x4){0.f, 0.f, 0.f, 0.f};
#pragma unroll
            for (int kh = 0; kh < 2; kh++) {
                bf16x8 b[4];
#pragma unroll
                for (int kt = 0; kt < 4; kt++)
                    b[kt] = base2[(size_t)(nt * 8 + kh * 4 + kt) * 64 + L];
#pragma unroll
                for (int hh = 0; hh < 2; hh++) {
                    int mh = hh * 16;
#pragma unroll
                    for (int kt = 0; kt < 4; kt++) {
                        bf16x8 a = *(const bf16x8*)&sMid[mh + l16][(kh * 4 + kt) * 32 + quad * 8];
                        acc[hh] = __builtin_amdgcn_mfma_f32_16x16x32_bf16(a, b[kt], acc[hh], 0, 0, 0);
                    }
                }
            }
            int c = nt * 16 + l16;
            float sc = g2[c] * rsqrtf(va2[c] + 1e-5f);
            float sh = (b2[c] - mu2[c]) * sc + be2[c];
#pragma unroll
            for (int hh = 0; hh < 2; hh++) {
#pragma unroll
                for (int r = 0; r < 4; r++) {
                    float o = fmaxf(acc[hh][r] * sc + sh, 0.f);
                    sIn[hh * 16 + quad * 4 + r][c] = f2bs(o);
                }
            }
        }
    }
    __syncthreads();

    // ---- coalesced epilogue: hb_out = hb_in + m (16 B/lane streams) ----
    {
        const u16x8* hs8 = (const u16x8*)hb_in;
#pragma unroll
        for (int idx = t; idx < 512; idx += 256) {
            int row = idx >> 4, seg = idx & 15;
            int node = node0 + row;
            if (node < n) {
                u16x8 m = *(const u16x8*)&sIn[row][seg * 8];
                u16x8 s = hs8[(size_t)node * 16 + seg];
                u16x8 o;
#pragma unroll
                for (int j = 0; j < 8; j++)
                    o[j] = f2bs(bs2f(s[j]) + bs2f(m[j]));
                *(u16x8*)(hb_out + (size_t)node * 128 + seg * 8) = o;
            }
        }
    }
}

// ---------------- pooling: run-length over sorted batch (bf16 in) ---------
// 16-node runs -> ~1563 blocks (~6/CU) so the serial load chain is short.
__global__ __launch_bounds__(256) void k_pool(const unsigned short* __restrict__ hb,
                                              const int* __restrict__ batch,
                                              float* __restrict__ pooled, int n)
{
    int c = threadIdx.x & 127;
    int half = threadIdx.x >> 7;
    int base = blockIdx.x * 32 + half * 16;
    float acc = 0.f;
    int curg = -1;
    for (int i = 0; i < 16; i++) {
        int node = base + i;
        if (node >= n) break;
        int g = batch[node];
        if (g != curg) {
            if (curg >= 0) atomicAdd(&pooled[(size_t)curg * 128 + c], acc);
            curg = g;
            acc = 0.f;
        }
        acc += bs2f(hb[(size_t)node * 128 + c]);
    }
    if (curg >= 0) atomicAdd(&pooled[(size_t)curg * 128 + c], acc);
}

__global__ __launch_bounds__(128) void k_head(const float* __restrict__ pooled,
                                              const float* __restrict__ W1,
                                              const float* __restrict__ b1,
                                              const float* __restrict__ W2,
                                              const float* __restrict__ b2,
                                              float* __restrict__ out)
{
    __shared__ float sp[128];
    __shared__ float st[128];
    int t = threadIdx.x;
    int g = blockIdx.x;
    sp[t] = pooled[(size_t)g * 128 + t];
    __syncthreads();
    float a = 0.f;
    for (int k = 0; k < 128; k++) a += sp[k] * W1[k * 128 + t];
    st[t] = fmaxf(a + b1[t], 0.f);
    __syncthreads();
    float o = 0.f;
    for (int k = 0; k < 128; k++) o += st[k] * W2[k * 128 + t];
    out[(size_t)g * 128 + t] = o + b2[t];
}

extern "C" void kernel_launch(void* const* d_in, const int* in_sizes, int n_in,
                              void* d_out, int out_size, void* d_ws, size_t ws_size,
                              hipStream_t stream)
{
    const float* x     = (const float*)d_in[0];
    const int*   ei    = (const int*)d_in[1];
    const int*   batch = (const int*)d_in[2];
    const float* W0    = (const float*)d_in[3];
    const float* b0    = (const float*)d_in[4];
    const float* mlpW1 = (const float*)d_in[5];
    const float* mlpb1 = (const float*)d_in[6];
    const float* bn1g  = (const float*)d_in[7];
    const float* bn1b  = (const float*)d_in[8];
    const float* bn1m  = (const float*)d_in[9];
    const float* bn1v  = (const float*)d_in[10];
    const float* mlpW2 = (const float*)d_in[11];
    const float* mlpb2 = (const float*)d_in[12];
    const float* ng    = (const float*)d_in[13];
    const float* nb    = (const float*)d_in[14];
    const float* nm    = (const float*)d_in[15];
    const float* nv    = (const float*)d_in[16];
    const float* W1    = (const float*)d_in[17];
    const float* b1    = (const float*)d_in[18];
    const float* W2    = (const float*)d_in[19];
    const float* b2    = (const float*)d_in[20];
    float* out = (float*)d_out;

    const int N = in_sizes[0] / 128;
    const int E = in_sizes[1] / 2;
    const int G = out_size / 128;
    const int* srcv = ei;
    const int* dstv = ei + E;

    // workspace layout
    float* pooled = (float*)d_ws;                               // G*128 f32
    unsigned short* hbA = (unsigned short*)(pooled + (size_t)G * 128); // N*128
    unsigned short* hbB = hbA + (size_t)N * 128;                // N*128
    short* pW1 = (short*)(hbB + (size_t)N * 128);               // 4*128*256
    short* pW2 = pW1 + 131072;                                  // 4*256*128
    short* pW0 = pW2 + 131072;                                  // 128*128
    int* ints  = (int*)(pW0 + 16384);
    int* deg      = ints;
    int* rowptr   = ints + N;
    int* cursor   = ints + 2 * N + 1;
    int* partials = ints + 3 * N + 1;                           // 256
    int* adj      = ints + 3 * N + 1 + 256;                     // E

    const int nodeBlocks = (N + 31) / 32;
    const int nbScan = (N + 255) / 256;
    const int eBlocks = (E + 255) / 256;
    const int packBlocks = (PK1 + PK2 + PK0 + 255) / 256;

    // ---- memsets up front (pooled only needed before k_pool) ----
    hipMemsetAsync(deg, 0, (size_t)N * sizeof(int), stream);
    hipMemsetAsync(pooled, 0, (size_t)G * 128 * sizeof(float), stream);

    // ---- CSR build + weight packing (merged) ----
    k_prep_a<<<eBlocks + packBlocks, 256, 0, stream>>>(
        dstv, deg, E, mlpW1, mlpW2, W0, pW1, pW2, pW0, eBlocks);
    k_scanA<<<nbScan, 256, 0, stream>>>(deg, partials, N);
    k_scanC<<<nbScan, 256, 0, stream>>>(deg, partials, rowptr, cursor, N, nbScan);
    // ---- CSR fill + encoder (merged) ----
    k_prep_b<<<eBlocks + nodeBlocks, 256, 0, stream>>>(
        srcv, dstv, cursor, adj, E, x, pW0, b0, hbA, N, eBlocks);

    // ---- layers: fused gather+MLP, ping-pong hbA/hbB ----
    unsigned short* hc = hbA;
    unsigned short* hn = hbB;
    for (int l = 0; l < 4; l++) {
        k_layer<<<nodeBlocks, 256, 0, stream>>>(
            hc, hn, rowptr, adj,
            pW1 + (size_t)l * 32768, mlpb1 + (size_t)l * 256,
            bn1g + (size_t)l * 256, bn1b + (size_t)l * 256,
            bn1m + (size_t)l * 256, bn1v + (size_t)l * 256,
            pW2 + (size_t)l * 32768, mlpb2 + (size_t)l * 128,
            ng + (size_t)l * 128, nb + (size_t)l * 128,
            nm + (size_t)l * 128, nv + (size_t)l * 128,
            N);
        unsigned short* tmp = hc; hc = hn; hn = tmp;
    }

    // ---- pool + head ----
    k_pool<<<(N + 31) / 32, 256, 0, stream>>>(hc, batch, pooled, N);
    k_head<<<G, 128, 0, stream>>>(pooled, W1, b1, W2, b2, out);
}

// Round 9
// 330.863 us; speedup vs baseline: 1.3120x; 1.0701x over previous
//
#include <hip/hip_runtime.h>
#include <hip/hip_bf16.h>

// ---------------------------------------------------------------------------
// GIN encoder. Residual stream in bf16 only (ping-pong A/B).
// Fused per-layer kernel (k_layer): gather + MLP + residual (round-8 config:
// 4 static streams x 2 episodes, launch_bounds(256,4), natural ~80 VGPR,
// 25.6KB LDS -> 6 blocks/CU).
// Round 9: atomic-free CSR fill via the RANK TRICK. The hist atomic in
// k_prep_a now returns the edge's rank within its dst bucket
// (rank[i] = atomicAdd(&deg[dst],1)); the fill in k_prep_b becomes
// adj[rowptr[dst] + rank[i]] = src[i] -- no returning atomic, no
// cursor-line bouncing across XCDs, fill threads fully pipelined.
// rank[] (E ints) is aliased onto hbB, which is first written in layer 0.
// ---------------------------------------------------------------------------

typedef short bf16x8 __attribute__((ext_vector_type(8)));
typedef unsigned short u16x8 __attribute__((ext_vector_type(8)));
typedef float f32x4 __attribute__((ext_vector_type(4)));

__device__ __forceinline__ float bs2f(unsigned short u) {
    return __uint_as_float(((unsigned)u) << 16);
}
__device__ __forceinline__ unsigned short f2bs(float f) {
    __hip_bfloat16 h = __float2bfloat16(f);
    return *reinterpret_cast<unsigned short*>(&h);
}

// masked packed unpack-accumulate: msk=~0u accumulates, 0u adds +0.0f
__device__ __forceinline__ void accm(float* acc, u16x8 v, unsigned msk) {
    union { u16x8 u; unsigned int w[4]; } cv;
    cv.u = v;
#pragma unroll
    for (int k = 0; k < 4; k++) {
        unsigned int d = cv.w[k] & msk;
        acc[2 * k]     += __uint_as_float(d << 16);
        acc[2 * k + 1] += __uint_as_float(d & 0xffff0000u);
    }
}

// ---------------- CSR scan kernels ----------------
__global__ __launch_bounds__(256) void k_scanA(const int* __restrict__ deg,
                                               int* __restrict__ partials, int n)
{
    int i = blockIdx.x * 256 + threadIdx.x;
    int v = (i < n) ? deg[i] : 0;
#pragma unroll
    for (int off = 32; off >= 1; off >>= 1) v += __shfl_down(v, off, 64);
    __shared__ int ws[4];
    int wave = threadIdx.x >> 6;
    if ((threadIdx.x & 63) == 0) ws[wave] = v;
    __syncthreads();
    if (threadIdx.x == 0)
        partials[blockIdx.x] = ws[0] + ws[1] + ws[2] + ws[3];
}

__global__ __launch_bounds__(256) void k_scanC(const int* __restrict__ deg,
                                               const int* __restrict__ partials,
                                               int* __restrict__ rowptr,
                                               int n, int nb)
{
    __shared__ int sp[256];
    __shared__ int s[256];
    int t = threadIdx.x;
    int pv = (t < nb) ? partials[t] : 0;
    sp[t] = pv;
    __syncthreads();
    for (int off = 1; off < 256; off <<= 1) {
        int u = (t >= off) ? sp[t - off] : 0;
        __syncthreads();
        sp[t] += u;
        __syncthreads();
    }
    int base = (blockIdx.x == 0) ? 0 : sp[blockIdx.x - 1];
    int i = blockIdx.x * 256 + t;
    int v = (i < n) ? deg[i] : 0;
    s[t] = v;
    __syncthreads();
    for (int off = 1; off < 256; off <<= 1) {
        int u = (t >= off) ? s[t - off] : 0;
        __syncthreads();
        s[t] += u;
        __syncthreads();
    }
    int inc = s[t];
    if (i < n) {
        int ex = base + inc - v;
        rowptr[i] = ex;
        if (i == n - 1) rowptr[n] = base + inc;
    }
}

// ---------------- weight packing helper ----------------
__device__ __forceinline__ void pack_one(const float* __restrict__ W,
                                         short* __restrict__ P,
                                         int id, int Kt, int Nt)
{
    int lane = id & 63;
    int t = id >> 6;
    int kt = t % Kt; t /= Kt;
    int nt = t % Nt; int l = t / Nt;
    int K = Kt * 32, N = Nt * 16;
    const float* Wl = W + (size_t)l * K * N;
    int n = nt * 16 + (lane & 15);
    int kbase = kt * 32 + (lane >> 4) * 8;
    bf16x8 v;
#pragma unroll
    for (int j = 0; j < 8; j++)
        v[j] = (short)f2bs(Wl[(size_t)(kbase + j) * N + n]);
    *(bf16x8*)(P + (size_t)id * 8) = v;
}

#define PK1 16384   // 4 layers * Nt16 * Kt4 * 64
#define PK2 16384   // 4 layers * Nt8  * Kt8 * 64
#define PK0 2048    // 1 layer  * Nt8  * Kt4 * 64

// ---------------- merged: edge hist+rank | weight packing ----------------
__global__ __launch_bounds__(256) void k_prep_a(
    const int* __restrict__ dst, int* __restrict__ deg,
    int* __restrict__ rank, int nE,
    const float* __restrict__ mlpW1, const float* __restrict__ mlpW2,
    const float* __restrict__ W0,
    short* __restrict__ pW1, short* __restrict__ pW2, short* __restrict__ pW0,
    int histBlocks)
{
    if ((int)blockIdx.x < histBlocks) {
        int i = blockIdx.x * 256 + threadIdx.x;
        if (i < nE) rank[i] = atomicAdd(&deg[dst[i]], 1);
    } else {
        int id = (blockIdx.x - histBlocks) * 256 + threadIdx.x;
        if (id < PK1) {
            pack_one(mlpW1, pW1, id, 4, 16);
        } else if (id < PK1 + PK2) {
            pack_one(mlpW2, pW2, id - PK1, 8, 8);
        } else if (id < PK1 + PK2 + PK0) {
            pack_one(W0, pW0, id - PK1 - PK2, 4, 8);
        }
    }
}

// ---------------- merged: atomic-free CSR fill | encoder ----------------
// encoder: hb = bf16(x@W0 + b0) via MFMA
__global__ __launch_bounds__(256) void k_prep_b(
    const int* __restrict__ src, const int* __restrict__ dst,
    const int* __restrict__ rowptr, const int* __restrict__ rank,
    int* __restrict__ adj, int nE,
    const float* __restrict__ x, const short* __restrict__ pW0,
    const float* __restrict__ b0, unsigned short* __restrict__ hb, int n,
    int fillBlocks)
{
    __shared__ unsigned short sX[32][136];
    if ((int)blockIdx.x < fillBlocks) {
        int i = blockIdx.x * 256 + threadIdx.x;
        if (i < nE) {
            int d = dst[i];
            adj[rowptr[d] + rank[i]] = src[i];
        }
        return;
    }
    const int t = threadIdx.x;
    const int w = t >> 6;
    const int L = t & 63;
    const int node0 = (blockIdx.x - fillBlocks) * 32;

    const float4* x4 = (const float4*)x;
    for (int i = t; i < 32 * 32; i += 256) {
        int m = i >> 5, cgi = i & 31;
        int node = node0 + m;
        float4 v = make_float4(0.f, 0.f, 0.f, 0.f);
        if (node < n) v = x4[(size_t)node * 32 + cgi];
        ushort4 p;
        p.x = f2bs(v.x); p.y = f2bs(v.y); p.z = f2bs(v.z); p.w = f2bs(v.w);
        *(ushort4*)&sX[m][cgi * 4] = p;
    }
    __syncthreads();

    const int quad = L >> 4;
    const int l16 = L & 15;
    const bf16x8* base = (const bf16x8*)pW0;

#pragma unroll
    for (int jj = 0; jj < 2; jj++) {
        int nt = w * 2 + jj;
        bf16x8 b[4];
#pragma unroll
        for (int kt = 0; kt < 4; kt++)
            b[kt] = base[(size_t)(nt * 4 + kt) * 64 + L];
        int c = nt * 16 + l16;
        float bc = b0[c];
#pragma unroll
        for (int hh = 0; hh < 2; hh++) {
            int mh = hh * 16;
            f32x4 acc = {0.f, 0.f, 0.f, 0.f};
#pragma unroll
            for (int kt = 0; kt < 4; kt++) {
                bf16x8 a = *(const bf16x8*)&sX[mh + l16][kt * 32 + quad * 8];
                acc = __builtin_amdgcn_mfma_f32_16x16x32_bf16(a, b[kt], acc, 0, 0, 0);
            }
#pragma unroll
            for (int r = 0; r < 4; r++) {
                int node = node0 + mh + quad * 4 + r;
                if (node < n)
                    hb[(size_t)node * 128 + c] = f2bs(acc[r] + bc);
            }
        }
    }
}

// ---------------- fused layer: gather + MLP + residual --------------------
// hb_out = hb_in + relu(BN2(W2 relu(BN1(W1 (hb_in + sum_neighbors)))))
// Gather: 4 static streams/wave (rows ep*4+{0..3}) x 2 episodes, clamped+
// masked 4-edge chunks (unroll-2 per stream), adj prefetched one chunk
// ahead. Lane layout: g = L>>4 picks 1 of 4 edges in the chunk, l16 = L&15
// is the 16B channel segment; 16 lanes cover one 256B node row.
// launch_bounds(256,4): 128-VGPR ceiling, allocator settles at natural ~80
// with no spill (R4/R5/R8); occupancy = min(LDS 25.6KB -> 6 blocks,
// 80 VGPR -> 6 waves/SIMD) = 6 blocks/CU.
__global__ __launch_bounds__(256, 4) void k_layer(
    const unsigned short* __restrict__ hb_in,
    unsigned short* __restrict__ hb_out,
    const int* __restrict__ rowptr, const int* __restrict__ adj,
    const short* __restrict__ pW1, const float* __restrict__ b1,
    const float* __restrict__ g1, const float* __restrict__ be1,
    const float* __restrict__ mu1, const float* __restrict__ va1,
    const short* __restrict__ pW2, const float* __restrict__ b2,
    const float* __restrict__ g2, const float* __restrict__ be2,
    const float* __restrict__ mu2, const float* __restrict__ va2,
    int n)
{
    __shared__ unsigned short sIn[32][136];    // gathered agg; reused for m out
    __shared__ unsigned short sMid[32][264];   // bf16 MLP hidden, pad 8
    const int t = threadIdx.x;
    const int w = t >> 6;
    const int L = t & 63;
    const int node0 = blockIdx.x * 32;
    const int g = L >> 4;
    const int l16 = L & 15;
    const int wrow = w * 8;

    // ---- gather phase: wave w fills sIn rows wrow..wrow+7 ----
    {
        const u16x8* hb8 = (const u16x8*)hb_in;
        const int base = node0 + wrow;

        // rowptr[base .. base+8], index-clamped so OOB rows degenerate
        // to empty ranges (rowptr[n] repeated).
        int rp[9];
#pragma unroll
        for (int j = 0; j < 9; j++) {
            int idx = base + j;
            rp[j] = rowptr[idx > n ? n : idx];
        }

#define CHUNK_INIT(S, EE, QQ)                                               \
        int e##S = (EE), q##S = (QQ);                                       \
        bool ok##S = e##S < q##S;                                           \
        int x##S##0 = e##S + g, x##S##1 = e##S + 4 + g;                     \
        int i##S##0 = adj[ok##S ? (x##S##0 < q##S ? x##S##0 : q##S - 1) : 0]; \
        int i##S##1 = adj[ok##S ? (x##S##1 < q##S ? x##S##1 : q##S - 1) : 0]; \
        float acc##S[8] = {0.f,0.f,0.f,0.f,0.f,0.f,0.f,0.f};

#define CHUNK_LOAD(S)                                                       \
        u16x8 r##S##0 = hb8[(unsigned)i##S##0 * 16u + l16];                 \
        u16x8 r##S##1 = hb8[(unsigned)i##S##1 * 16u + l16];

#define CHUNK_MASK(S)                                                       \
        unsigned m##S##0 = (ok##S && e##S + g < q##S)     ? ~0u : 0u;       \
        unsigned m##S##1 = (ok##S && e##S + 4 + g < q##S) ? ~0u : 0u;

#define CHUNK_PREF(S)                                                       \
        int ne##S = ok##S ? e##S + 8 : e##S;                                \
        bool nok##S = ne##S < q##S;                                         \
        int nx##S##0 = ne##S + g, nx##S##1 = ne##S + 4 + g;                 \
        int ni##S##0 = adj[nok##S ? (nx##S##0 < q##S ? nx##S##0 : q##S - 1) : 0]; \
        int ni##S##1 = adj[nok##S ? (nx##S##1 < q##S ? nx##S##1 : q##S - 1) : 0];

#define CHUNK_ACC(S)                                                        \
        accm(acc##S, r##S##0, m##S##0);                                     \
        accm(acc##S, r##S##1, m##S##1);

#define CHUNK_ROT(S)                                                        \
        e##S = ne##S; ok##S = nok##S; i##S##0 = ni##S##0; i##S##1 = ni##S##1;

#define SELF_LOAD(S, NODE)                                                  \
        u16x8 self##S;                                                      \
        {                                                                   \
            _Pragma("unroll")                                               \
            for (int j = 0; j < 8; j++) self##S[j] = 0;                     \
            if ((NODE) < n) self##S = hb8[(unsigned)(NODE) * 16u + l16];    \
        }

#define STREAM_FIN(S, ROWIDX)                                               \
        {                                                                   \
            u16x8 o;                                                        \
            _Pragma("unroll")                                               \
            for (int j = 0; j < 8; j++) {                                   \
                float vv = acc##S[j];                                       \
                vv += __shfl_xor(vv, 16, 64);                               \
                vv += __shfl_xor(vv, 32, 64);                               \
                o[j] = f2bs(vv + bs2f(self##S[j]));                         \
            }                                                               \
            if (g == 0) *(u16x8*)&sIn[(ROWIDX)][l16 * 8] = o;               \
        }

#pragma unroll
        for (int ep = 0; ep < 2; ep++) {
            const int r0 = ep * 4;
            CHUNK_INIT(A, rp[r0 + 0], rp[r0 + 1])
            CHUNK_INIT(B, rp[r0 + 1], rp[r0 + 2])
            CHUNK_INIT(C, rp[r0 + 2], rp[r0 + 3])
            CHUNK_INIT(D, rp[r0 + 3], rp[r0 + 4])

            while (okA | okB | okC | okD) {
                CHUNK_LOAD(A) CHUNK_LOAD(B) CHUNK_LOAD(C) CHUNK_LOAD(D)
                CHUNK_MASK(A) CHUNK_MASK(B) CHUNK_MASK(C) CHUNK_MASK(D)
                CHUNK_PREF(A) CHUNK_PREF(B) CHUNK_PREF(C) CHUNK_PREF(D)
                CHUNK_ACC(A) CHUNK_ACC(B) CHUNK_ACC(C) CHUNK_ACC(D)
                CHUNK_ROT(A) CHUNK_ROT(B) CHUNK_ROT(C) CHUNK_ROT(D)
            }

            SELF_LOAD(A, base + r0 + 0)
            SELF_LOAD(B, base + r0 + 1)
            SELF_LOAD(C, base + r0 + 2)
            SELF_LOAD(D, base + r0 + 3)
            STREAM_FIN(A, wrow + r0 + 0)
            STREAM_FIN(B, wrow + r0 + 1)
            STREAM_FIN(C, wrow + r0 + 2)
            STREAM_FIN(D, wrow + r0 + 3)
        }
#undef CHUNK_INIT
#undef CHUNK_LOAD
#undef CHUNK_MASK
#undef CHUNK_PREF
#undef CHUNK_ACC
#undef CHUNK_ROT
#undef SELF_LOAD
#undef STREAM_FIN
    }
    __syncthreads();

    const int quad = L >> 4;

    // ---- phase 1: sMid = relu(BN1(sIn @ W1 + b1)), 32x256, K=128 ----
    {
        const bf16x8* base1 = (const bf16x8*)pW1;
#pragma unroll
        for (int j = 0; j < 4; j++) {
            int nt = w * 4 + j;
            bf16x8 b[4];
#pragma unroll
            for (int kt = 0; kt < 4; kt++)
                b[kt] = base1[(size_t)(nt * 4 + kt) * 64 + L];
            int c = nt * 16 + l16;
            float sc = g1[c] * rsqrtf(va1[c] + 1e-5f);
            float sh = (b1[c] - mu1[c]) * sc + be1[c];
#pragma unroll
            for (int hh = 0; hh < 2; hh++) {
                int mh = hh * 16;
                f32x4 acc = {0.f, 0.f, 0.f, 0.f};
#pragma unroll
                for (int kt = 0; kt < 4; kt++) {
                    bf16x8 a = *(const bf16x8*)&sIn[mh + l16][kt * 32 + quad * 8];
                    acc = __builtin_amdgcn_mfma_f32_16x16x32_bf16(a, b[kt], acc, 0, 0, 0);
                }
#pragma unroll
                for (int r = 0; r < 4; r++) {
                    float v = fmaxf(acc[r] * sc + sh, 0.f);
                    sMid[mh + quad * 4 + r][c] = f2bs(v);
                }
            }
        }
    }
    __syncthreads();

    // ---- phase 2: m = relu(BN2(sMid @ W2 + b2)) -> staged into sIn ----
    {
        const bf16x8* base2 = (const bf16x8*)pW2;
#pragma unroll
        for (int jj = 0; jj < 2; jj++) {
            int nt = w * 2 + jj;
            f32x4 acc[2];
            acc[0] = (f32x4){0.f, 0.f, 0.f, 0.f};
            acc[1] = (f32x4){0.f, 0.f, 0.f, 0.f};
#pragma unroll
            for (int kh = 0; kh < 2; kh++) {
                bf16x8 b[4];
#pragma unroll
                for (int kt = 0; kt < 4; kt++)
                    b[kt] = base2[(size_t)(nt * 8 + kh * 4 + kt) * 64 + L];
#pragma unroll
                for (int hh = 0; hh < 2; hh++) {
                    int mh = hh * 16;
#pragma unroll
                    for (int kt = 0; kt < 4; kt++) {
                        bf16x8 a = *(const bf16x8*)&sMid[mh + l16][(kh * 4 + kt) * 32 + quad * 8];
                        acc[hh] = __builtin_amdgcn_mfma_f32_16x16x32_bf16(a, b[kt], acc[hh], 0, 0, 0);
                    }
                }
            }
            int c = nt * 16 + l16;
            float sc = g2[c] * rsqrtf(va2[c] + 1e-5f);
            float sh = (b2[c] - mu2[c]) * sc + be2[c];
#pragma unroll
            for (int hh = 0; hh < 2; hh++) {
#pragma unroll
                for (int r = 0; r < 4; r++) {
                    float o = fmaxf(acc[hh][r] * sc + sh, 0.f);
                    sIn[hh * 16 + quad * 4 + r][c] = f2bs(o);
                }
            }
        }
    }
    __syncthreads();

    // ---- coalesced epilogue: hb_out = hb_in + m (16 B/lane streams) ----
    {
        const u16x8* hs8 = (const u16x8*)hb_in;
#pragma unroll
        for (int idx = t; idx < 512; idx += 256) {
            int row = idx >> 4, seg = idx & 15;
            int node = node0 + row;
            if (node < n) {
                u16x8 m = *(const u16x8*)&sIn[row][seg * 8];
                u16x8 s = hs8[(size_t)node * 16 + seg];
                u16x8 o;
#pragma unroll
                for (int j = 0; j < 8; j++)
                    o[j] = f2bs(bs2f(s[j]) + bs2f(m[j]));
                *(u16x8*)(hb_out + (size_t)node * 128 + seg * 8) = o;
            }
        }
    }
}

// ---------------- pooling: run-length over sorted batch (bf16 in) ---------
// 16-node runs -> ~1563 blocks (~6/CU) so the serial load chain is short.
__global__ __launch_bounds__(256) void k_pool(const unsigned short* __restrict__ hb,
                                              const int* __restrict__ batch,
                                              float* __restrict__ pooled, int n)
{
    int c = threadIdx.x & 127;
    int half = threadIdx.x >> 7;
    int base = blockIdx.x * 32 + half * 16;
    float acc = 0.f;
    int curg = -1;
    for (int i = 0; i < 16; i++) {
        int node = base + i;
        if (node >= n) break;
        int g = batch[node];
        if (g != curg) {
            if (curg >= 0) atomicAdd(&pooled[(size_t)curg * 128 + c], acc);
            curg = g;
            acc = 0.f;
        }
        acc += bs2f(hb[(size_t)node * 128 + c]);
    }
    if (curg >= 0) atomicAdd(&pooled[(size_t)curg * 128 + c], acc);
}

__global__ __launch_bounds__(128) void k_head(const float* __restrict__ pooled,
                                              const float* __restrict__ W1,
                                              const float* __restrict__ b1,
                                              const float* __restrict__ W2,
                                              const float* __restrict__ b2,
                                              float* __restrict__ out)
{
    __shared__ float sp[128];
    __shared__ float st[128];
    int t = threadIdx.x;
    int g = blockIdx.x;
    sp[t] = pooled[(size_t)g * 128 + t];
    __syncthreads();
    float a = 0.f;
    for (int k = 0; k < 128; k++) a += sp[k] * W1[k * 128 + t];
    st[t] = fmaxf(a + b1[t], 0.f);
    __syncthreads();
    float o = 0.f;
    for (int k = 0; k < 128; k++) o += st[k] * W2[k * 128 + t];
    out[(size_t)g * 128 + t] = o + b2[t];
}

extern "C" void kernel_launch(void* const* d_in, const int* in_sizes, int n_in,
                              void* d_out, int out_size, void* d_ws, size_t ws_size,
                              hipStream_t stream)
{
    const float* x     = (const float*)d_in[0];
    const int*   ei    = (const int*)d_in[1];
    const int*   batch = (const int*)d_in[2];
    const float* W0    = (const float*)d_in[3];
    const float* b0    = (const float*)d_in[4];
    const float* mlpW1 = (const float*)d_in[5];
    const float* mlpb1 = (const float*)d_in[6];
    const float* bn1g  = (const float*)d_in[7];
    const float* bn1b  = (const float*)d_in[8];
    const float* bn1m  = (const float*)d_in[9];
    const float* bn1v  = (const float*)d_in[10];
    const float* mlpW2 = (const float*)d_in[11];
    const float* mlpb2 = (const float*)d_in[12];
    const float* ng    = (const float*)d_in[13];
    const float* nb    = (const float*)d_in[14];
    const float* nm    = (const float*)d_in[15];
    const float* nv    = (const float*)d_in[16];
    const float* W1    = (const float*)d_in[17];
    const float* b1    = (const float*)d_in[18];
    const float* W2    = (const float*)d_in[19];
    const float* b2    = (const float*)d_in[20];
    float* out = (float*)d_out;

    const int N = in_sizes[0] / 128;
    const int E = in_sizes[1] / 2;
    const int G = out_size / 128;
    const int* srcv = ei;
    const int* dstv = ei + E;

    // workspace layout
    float* pooled = (float*)d_ws;                               // G*128 f32
    unsigned short* hbA = (unsigned short*)(pooled + (size_t)G * 128); // N*128
    unsigned short* hbB = hbA + (size_t)N * 128;                // N*128
    short* pW1 = (short*)(hbB + (size_t)N * 128);               // 4*128*256
    short* pW2 = pW1 + 131072;                                  // 4*256*128
    short* pW0 = pW2 + 131072;                                  // 128*128
    int* ints  = (int*)(pW0 + 16384);
    int* deg      = ints;
    int* rowptr   = ints + N;
    int* partials = ints + 2 * N + 1;                           // 256
    int* adj      = ints + 2 * N + 1 + 256;                     // E
    // rank aliases hbB: consumed by k_prep_b's fill BEFORE layer 0
    // writes hbB (single stream => ordered). E ints = 2.56MB << 12.8MB.
    int* rank = (int*)hbB;

    const int nodeBlocks = (N + 31) / 32;
    const int nbScan = (N + 255) / 256;
    const int eBlocks = (E + 255) / 256;
    const int packBlocks = (PK1 + PK2 + PK0 + 255) / 256;

    // ---- memsets up front ----
    hipMemsetAsync(deg, 0, (size_t)N * sizeof(int), stream);
    hipMemsetAsync(pooled, 0, (size_t)G * 128 * sizeof(float), stream);

    // ---- CSR hist+rank + weight packing (merged) ----
    k_prep_a<<<eBlocks + packBlocks, 256, 0, stream>>>(
        dstv, deg, rank, E, mlpW1, mlpW2, W0, pW1, pW2, pW0, eBlocks);
    k_scanA<<<nbScan, 256, 0, stream>>>(deg, partials, N);
    k_scanC<<<nbScan, 256, 0, stream>>>(deg, partials, rowptr, N, nbScan);
    // ---- atomic-free CSR fill + encoder (merged) ----
    k_prep_b<<<eBlocks + nodeBlocks, 256, 0, stream>>>(
        srcv, dstv, rowptr, rank, adj, E, x, pW0, b0, hbA, N, eBlocks);

    // ---- layers: fused gather+MLP, ping-pong hbA/hbB ----
    unsigned short* hc = hbA;
    unsigned short* hn = hbB;
    for (int l = 0; l < 4; l++) {
        k_layer<<<nodeBlocks, 256, 0, stream>>>(
            hc, hn, rowptr, adj,
            pW1 + (size_t)l * 32768, mlpb1 + (size_t)l * 256,
            bn1g + (size_t)l * 256, bn1b + (size_t)l * 256,
            bn1m + (size_t)l * 256, bn1v + (size_t)l * 256,
            pW2 + (size_t)l * 32768, mlpb2 + (size_t)l * 128,
            ng + (size_t)l * 128, nb + (size_t)l * 128,
            nm + (size_t)l * 128, nv + (size_t)l * 128,
            N);
        unsigned short* tmp = hc; hc = hn; hn = tmp;
    }

    // ---- pool + head ----
    k_pool<<<(N + 31) / 32, 256, 0, stream>>>(hc, batch, pooled, N);
    k_head<<<G, 128, 0, stream>>>(pooled, W1, b1, W2, b2, out);
}